// Round 11
// baseline (8274.699 us; speedup 1.0000x reference)
//
#include <hip/hip_runtime.h>
#include <float.h>

#define NB 64
#define NP 1024
#define KNN 10
#define SCAP 30   // survivors per (point, j-chunk)

__device__ __forceinline__ float lrelu(float v){ return v >= 0.0f ? v : 0.01f*v; }

// sorted-ascending bubble insert; strict < keeps earlier-inserted (lower j) on ties.
// Only static data flow (no runtime-indexed register arrays — R6 spill lesson).
#define TOP10_INSERT(dk_, ik_, bd_, bi_)              \
  { float dk=dk_; int ik=ik_;                         \
    _Pragma("unroll")                                 \
    for (int s=0;s<KNN;++s){                          \
      bool sw = dk < bd_[s];                          \
      float td=bd_[s]; int ti=bi_[s];                 \
      bd_[s]=sw?dk:td; bi_[s]=sw?ik:ti;               \
      dk=sw?td:dk;     ik=sw?ti:ik; } }

// ---------------- fused prep: build xx, wcomb, zero fmean ----------------
__global__ void prep_fused(const float* __restrict__ x, const float* __restrict__ pos,
                           const float* __restrict__ w2,
                           float* __restrict__ xx, float* __restrict__ wcomb,
                           float* __restrict__ fmean){
  int tid = blockIdx.x*256 + threadIdx.x;   // grid 368 -> 94208 threads
  if (tid < 65536){
    float4 v;
    v.x = x[tid];
    v.y = pos[3*tid+0];
    v.z = pos[3*tid+1];
    v.w = pos[3*tid+2];
    ((float4*)xx)[tid] = v;
  } else if (tid < 65536+16384){
    int i = tid - 65536;
    int op = i >> 6, c = i & 63;
    if (op < 128){
      wcomb[i] = w2[(64+c)*128 + op];
    } else {
      int o = op - 128;
      wcomb[i] = w2[c*128 + o] - w2[(64+c)*128 + o];
    }
  } else {
    int i = tid - 65536 - 16384;
    if (i < NB*192) fmean[i] = 0.0f;
  }
}

// ---------------- qr1: q1 = xx@Wbot, r1 = xx@(Wtop-Wbot)+b1a ----------------
// w1a is (8,64): rows 0..3 = Wtop (xi part), rows 4..7 = Wbot (xj-xi part).
__global__ __launch_bounds__(256,4) void qr1_kernel(const float* __restrict__ xx,
    const float* __restrict__ w1a, const float* __restrict__ b1a,
    float* __restrict__ q1, float* __restrict__ r1){
  __shared__ alignas(16) float swt[256];  // Wtop-Wbot (after in-place sub)
  __shared__ alignas(16) float swb[256];  // Wbot
  __shared__ float sb[64];
  int t = threadIdx.x;
  {
    float top = w1a[t];
    float bot = w1a[256 + t];
    swb[t] = bot;
    swt[t] = top - bot;
  }
  if (t < 64) sb[t] = b1a[t];
  __syncthreads();
  int n = blockIdx.x*256 + t;
  float4 fi = ((const float4*)xx)[n];
  #pragma unroll 2
  for (int o=0;o<64;o+=4){
    float4 q, r;
    {
      float4 w0 = *(const float4*)&swb[0*64+o];
      float4 w1 = *(const float4*)&swb[1*64+o];
      float4 w2v = *(const float4*)&swb[2*64+o];
      float4 w3 = *(const float4*)&swb[3*64+o];
      q.x = fmaf(fi.x,w0.x, fmaf(fi.y,w1.x, fmaf(fi.z,w2v.x, fi.w*w3.x)));
      q.y = fmaf(fi.x,w0.y, fmaf(fi.y,w1.y, fmaf(fi.z,w2v.y, fi.w*w3.y)));
      q.z = fmaf(fi.x,w0.z, fmaf(fi.y,w1.z, fmaf(fi.z,w2v.z, fi.w*w3.z)));
      q.w = fmaf(fi.x,w0.w, fmaf(fi.y,w1.w, fmaf(fi.z,w2v.w, fi.w*w3.w)));
    }
    {
      float4 w0 = *(const float4*)&swt[0*64+o];
      float4 w1 = *(const float4*)&swt[1*64+o];
      float4 w2v = *(const float4*)&swt[2*64+o];
      float4 w3 = *(const float4*)&swt[3*64+o];
      r.x = sb[o+0] + fmaf(fi.x,w0.x, fmaf(fi.y,w1.x, fmaf(fi.z,w2v.x, fi.w*w3.x)));
      r.y = sb[o+1] + fmaf(fi.x,w0.y, fmaf(fi.y,w1.y, fmaf(fi.z,w2v.y, fi.w*w3.y)));
      r.z = sb[o+2] + fmaf(fi.x,w0.z, fmaf(fi.y,w1.z, fmaf(fi.z,w2v.z, fi.w*w3.z)));
      r.w = sb[o+3] + fmaf(fi.x,w0.w, fmaf(fi.y,w1.w, fmaf(fi.z,w2v.w, fi.w*w3.w)));
    }
    *(float4*)&q1[(size_t)n*64+o] = q;
    *(float4*)&r1[(size_t)n*64+o] = r;
  }
}

// ---------------- knn1: 4-dim features, 4 i-quarters x 4 j-quarters ----------------
__global__ __launch_bounds__(256,2) void knn1_kernel(const float* __restrict__ xx,
                                                     float* __restrict__ bdh1,
                                                     int* __restrict__ bih1){
  __shared__ alignas(16) float sf[256*4];   // 4 KB j-quarter points
  __shared__ float ssq[256];
  int bid = blockIdx.x;        // 1024 = 64 b x 4 iq x 4 jq
  int b  = bid >> 4;
  int iq = (bid >> 2) & 3;
  int jq = bid & 3;
  int t = threadIdx.x;
  {
    float4 v = ((const float4*)xx)[(size_t)b*NP + jq*256 + t];
    ((float4*)sf)[t] = v;
    ssq[t] = ((v.x*v.x + v.y*v.y) + v.z*v.z) + v.w*v.w;
  }
  __syncthreads();
  int il = iq*256 + t;
  int n = b*NP + il;
  float4 fi = ((const float4*)xx)[n];
  float sqi = ((fi.x*fi.x + fi.y*fi.y) + fi.z*fi.z) + fi.w*fi.w;
  float bd[KNN]; int bi[KNN];
  #pragma unroll
  for (int s=0;s<KNN;++s){ bd[s]=FLT_MAX; bi[s]=0; }
  #pragma unroll 1
  for (int j=0;j<256;++j){
    float4 fj = ((float4*)sf)[j];
    float dot = fi.x*fj.x + fi.y*fj.y + fi.z*fj.z + fi.w*fj.w;
    float d2 = (sqi + ssq[j]) - 2.0f*dot;
    if (d2 < bd[KNN-1]){
      TOP10_INSERT(d2, jq*256+j, bd, bi);
    }
  }
  #pragma unroll
  for (int s=0;s<KNN;++s){
    bdh1[((size_t)n*4 + jq)*KNN + s] = bd[s];
    bih1[((size_t)n*4 + jq)*KNN + s] = bi[s];
  }
}

// ---------------- fold-merge of 4 sorted lists (ties -> lower list = lower j) ----------------
__global__ void merge4_kernel(const float* __restrict__ bdh, const int* __restrict__ bih,
                              int* __restrict__ idx){
  int n = blockIdx.x*256 + threadIdx.x;
  float A[KNN]; int Ai[KNN];
  #pragma unroll
  for (int s=0;s<KNN;++s){
    A[s]  = bdh[(size_t)n*4*KNN + s];
    Ai[s] = bih[(size_t)n*4*KNN + s];
  }
  #pragma unroll
  for (int q=1;q<4;++q){
    float T[KNN]; int Ti[KNN];
    #pragma unroll
    for (int s=0;s<KNN;++s){
      T[s]  = bdh[((size_t)n*4+q)*KNN + s];
      Ti[s] = bih[((size_t)n*4+q)*KNN + s];
    }
    float O[KNN]; int Oi[KNN];
    #pragma unroll
    for (int s=0;s<KNN;++s){
      bool ta = A[0] <= T[0];
      O[s]  = ta ? A[0]  : T[0];
      Oi[s] = ta ? Ai[0] : Ti[0];
      #pragma unroll
      for (int u=0;u<KNN-1;++u){
        A[u]  = ta ? A[u+1]  : A[u];
        Ai[u] = ta ? Ai[u+1] : Ai[u];
        T[u]  = ta ? T[u]    : T[u+1];
        Ti[u] = ta ? Ti[u]   : Ti[u+1];
      }
    }
    #pragma unroll
    for (int s=0;s<KNN;++s){ A[s]=O[s]; Ai[s]=Oi[s]; }
  }
  #pragma unroll
  for (int s=0;s<KNN;++s) idx[(size_t)n*KNN+s] = Ai[s];
}

// ---------------- edgeconv1: 2 threads/point, 2-edge batching, shfl h-exchange ----------------
// Layer a factored out: h1 = lrelu(r_i + q_j). Each weight ds_read_b128 feeds
// 8 FMAs (2 edges x 4 outputs) vs 4 before -> LDS instr halved. No hx LDS, no
// per-k barriers. All register arrays statically indexed (c-loops fully
// unrolled) — R6 lesson.
__global__ __launch_bounds__(256,1) void edgeconv1_kernel(
    const float* __restrict__ q1, const float* __restrict__ r1,
    const int* __restrict__ idx1,
    const float* __restrict__ w1b, const float* __restrict__ b1b,
    const float* __restrict__ w1c, const float* __restrict__ b1c,
    float* __restrict__ x1, float* __restrict__ sq2){
  __shared__ alignas(16) float swb[4096];    // 16 KB w1b [c][o]
  __shared__ alignas(16) float swc[4096];    // 16 KB w1c [c][o]
  __shared__ float sbb[64], sbc[64];
  int t = threadIdx.x;
  for (int i=t; i<1024; i+=256) ((float4*)swb)[i] = ((const float4*)w1b)[i];
  for (int i=t; i<1024; i+=256) ((float4*)swc)[i] = ((const float4*)w1c)[i];
  if (t < 64){ sbb[t]=b1b[t]; sbc[t]=b1c[t]; }
  __syncthreads();

  int p  = t >> 1;          // local point 0..127
  int hf = t & 1;           // output half
  int ob = hf*32;
  int obx = ob ^ 32;        // partner's channel base
  int b  = blockIdx.x >> 3; // batch
  int g  = blockIdx.x & 7;  // point group
  int n  = b*NP + g*128 + p;

  float acc[32];
  #pragma unroll
  for (int o=0;o<32;++o) acc[o]=0.0f;

  #pragma unroll 1
  for (int kp=0; kp<5; ++kp){
    int j0 = idx1[n*KNN + kp*2];
    int j1 = idx1[n*KNN + kp*2 + 1];

    // h1 (own 32 channels) for both edges: lrelu(r_i + q_j)
    float h0[32], h1v[32];
    {
      const float4* rp  = (const float4*)(r1 + (size_t)n*64 + ob);
      const float4* q0p = (const float4*)(q1 + ((size_t)(b*NP) + j0)*64 + ob);
      const float4* q1p = (const float4*)(q1 + ((size_t)(b*NP) + j1)*64 + ob);
      #pragma unroll
      for (int c4=0;c4<8;++c4){
        float4 rv = rp[c4];
        float4 a0 = q0p[c4];
        float4 a1 = q1p[c4];
        h0[c4*4+0]=lrelu(rv.x+a0.x); h0[c4*4+1]=lrelu(rv.y+a0.y);
        h0[c4*4+2]=lrelu(rv.z+a0.z); h0[c4*4+3]=lrelu(rv.w+a0.w);
        h1v[c4*4+0]=lrelu(rv.x+a1.x); h1v[c4*4+1]=lrelu(rv.y+a1.y);
        h1v[c4*4+2]=lrelu(rv.z+a1.z); h1v[c4*4+3]=lrelu(rv.w+a1.w);
      }
    }

    // ---- layer b: 64 -> my 32 outputs, both edges share weight reads
    float pr0[32], pr1[32];
    #pragma unroll
    for (int o=0;o<32;++o){ pr0[o]=sbb[ob+o]; pr1[o]=sbb[ob+o]; }
    #pragma unroll
    for (int c=0;c<32;++c){
      float ho0 = h0[c],  ho1 = h1v[c];
      float hp0 = __shfl_xor(h0[c], 1);
      float hp1 = __shfl_xor(h1v[c], 1);
      #pragma unroll
      for (int o4=0;o4<8;++o4){
        float4 wo = *(const float4*)&swb[(ob +c)*64 + ob + o4*4];
        float4 wp = *(const float4*)&swb[(obx+c)*64 + ob + o4*4];
        pr0[o4*4+0]=fmaf(ho0,wo.x,fmaf(hp0,wp.x,pr0[o4*4+0]));
        pr0[o4*4+1]=fmaf(ho0,wo.y,fmaf(hp0,wp.y,pr0[o4*4+1]));
        pr0[o4*4+2]=fmaf(ho0,wo.z,fmaf(hp0,wp.z,pr0[o4*4+2]));
        pr0[o4*4+3]=fmaf(ho0,wo.w,fmaf(hp0,wp.w,pr0[o4*4+3]));
        pr1[o4*4+0]=fmaf(ho1,wo.x,fmaf(hp1,wp.x,pr1[o4*4+0]));
        pr1[o4*4+1]=fmaf(ho1,wo.y,fmaf(hp1,wp.y,pr1[o4*4+1]));
        pr1[o4*4+2]=fmaf(ho1,wo.z,fmaf(hp1,wp.z,pr1[o4*4+2]));
        pr1[o4*4+3]=fmaf(ho1,wo.w,fmaf(hp1,wp.w,pr1[o4*4+3]));
      }
    }
    // h2 = lrelu(pr), reuse h arrays
    #pragma unroll
    for (int o=0;o<32;++o){ h0[o]=lrelu(pr0[o]); h1v[o]=lrelu(pr1[o]); }

    // ---- layer c: same pattern with swc
    #pragma unroll
    for (int o=0;o<32;++o){ pr0[o]=sbc[ob+o]; pr1[o]=sbc[ob+o]; }
    #pragma unroll
    for (int c=0;c<32;++c){
      float ho0 = h0[c],  ho1 = h1v[c];
      float hp0 = __shfl_xor(h0[c], 1);
      float hp1 = __shfl_xor(h1v[c], 1);
      #pragma unroll
      for (int o4=0;o4<8;++o4){
        float4 wo = *(const float4*)&swc[(ob +c)*64 + ob + o4*4];
        float4 wp = *(const float4*)&swc[(obx+c)*64 + ob + o4*4];
        pr0[o4*4+0]=fmaf(ho0,wo.x,fmaf(hp0,wp.x,pr0[o4*4+0]));
        pr0[o4*4+1]=fmaf(ho0,wo.y,fmaf(hp0,wp.y,pr0[o4*4+1]));
        pr0[o4*4+2]=fmaf(ho0,wo.z,fmaf(hp0,wp.z,pr0[o4*4+2]));
        pr0[o4*4+3]=fmaf(ho0,wo.w,fmaf(hp0,wp.w,pr0[o4*4+3]));
        pr1[o4*4+0]=fmaf(ho1,wo.x,fmaf(hp1,wp.x,pr1[o4*4+0]));
        pr1[o4*4+1]=fmaf(ho1,wo.y,fmaf(hp1,wp.y,pr1[o4*4+1]));
        pr1[o4*4+2]=fmaf(ho1,wo.z,fmaf(hp1,wp.z,pr1[o4*4+2]));
        pr1[o4*4+3]=fmaf(ho1,wo.w,fmaf(hp1,wp.w,pr1[o4*4+3]));
      }
    }
    #pragma unroll
    for (int o=0;o<32;++o) acc[o] += lrelu(pr0[o]) + lrelu(pr1[o]);
  }

  float s = 0.0f;
  #pragma unroll
  for (int o=0;o<32;o+=4){
    float4 v; v.x=acc[o]; v.y=acc[o+1]; v.z=acc[o+2]; v.w=acc[o+3];
    *(float4*)&x1[(size_t)n*64 + ob + o] = v;
    s = fmaf(acc[o],acc[o], fmaf(acc[o+1],acc[o+1], fmaf(acc[o+2],acc[o+2], fmaf(acc[o+3],acc[o+3], s))));
  }
  s += __shfl_xor(s, 1);
  if (hf == 0) sq2[n] = s;
}

// ---------------- knn2 phase A: exact top-10 over j in [0,256) + threshold ----------------
__global__ __launch_bounds__(256,1) void knn2_thresh(const float* __restrict__ x1,
    const float* __restrict__ sq2,
    float* __restrict__ seed_d, int* __restrict__ seed_i, float* __restrict__ Tout){
  __shared__ alignas(16) float sj[64*64];    // 16 KB
  __shared__ float ssq[64];
  int b  = blockIdx.x >> 2;
  int ig = blockIdx.x & 3;
  int t = threadIdx.x;
  int n = b*NP + ig*256 + t;
  float xi[64];
  #pragma unroll
  for (int c=0;c<64;c+=4){
    float4 v = *(const float4*)&x1[(size_t)n*64+c];
    xi[c]=v.x; xi[c+1]=v.y; xi[c+2]=v.z; xi[c+3]=v.w;
  }
  float sqi = sq2[n];
  float bd[KNN]; int bi[KNN];
  #pragma unroll
  for (int s=0;s<KNN;++s){ bd[s]=FLT_MAX; bi[s]=0; }
  for (int tile=0; tile<4; ++tile){
    __syncthreads();
    const float4* src = (const float4*)(x1 + ((size_t)b*NP + tile*64)*64);
    for (int u=t; u<1024; u+=256) ((float4*)sj)[u] = src[u];
    if (t < 64) ssq[t] = sq2[b*NP + tile*64 + t];
    __syncthreads();
    #pragma unroll 1
    for (int j=0;j<64;++j){
      float dot = 0.0f;
      #pragma unroll
      for (int c=0;c<64;c+=4){
        float4 v = *(const float4*)&sj[j*64+c];
        dot = fmaf(xi[c+0],v.x,dot); dot = fmaf(xi[c+1],v.y,dot);
        dot = fmaf(xi[c+2],v.z,dot); dot = fmaf(xi[c+3],v.w,dot);
      }
      float d2 = (sqi + ssq[j]) - 2.0f*dot;
      if (d2 < bd[KNN-1]){
        TOP10_INSERT(d2, tile*64+j, bd, bi);
      }
    }
  }
  #pragma unroll
  for (int s=0;s<KNN;++s){
    seed_d[(size_t)n*KNN + s] = bd[s];
    seed_i[(size_t)n*KNN + s] = bi[s];
  }
  Tout[n] = bd[KNN-1];
}

// ---------------- knn2 phase B: filtered scan of j in [256,1024), 4 chunks ----------------
__global__ __launch_bounds__(256,2) void knn2_scan(const float* __restrict__ x1,
    const float* __restrict__ sq2, const float* __restrict__ Tin,
    float2* __restrict__ surv, int* __restrict__ cnt4){
  __shared__ alignas(16) float sj[96*64];    // 24 KB
  __shared__ float ssq[96];
  int bid = blockIdx.x;     // 1024 = 64 b x 4 ig x 4 jc
  int b  = bid >> 4;
  int ig = (bid >> 2) & 3;
  int jc = bid & 3;
  int t = threadIdx.x;
  int n = b*NP + ig*256 + t;
  float xi[64];
  #pragma unroll
  for (int c=0;c<64;c+=4){
    float4 v = *(const float4*)&x1[(size_t)n*64+c];
    xi[c]=v.x; xi[c+1]=v.y; xi[c+2]=v.z; xi[c+3]=v.w;
  }
  float sqi = sq2[n];
  float thr = Tin[n];
  int cnt = 0;
  float2* mybuf = surv + ((size_t)n*4 + jc)*SCAP;
  int jbase0 = 256 + jc*192;
  for (int tile=0; tile<2; ++tile){
    int jb = jbase0 + tile*96;
    __syncthreads();
    const float4* src = (const float4*)(x1 + ((size_t)b*NP + jb)*64);
    for (int u=t; u<1536; u+=256) ((float4*)sj)[u] = src[u];
    if (t < 96) ssq[t] = sq2[b*NP + jb + t];
    __syncthreads();
    #pragma unroll 1
    for (int j=0;j<96;++j){
      float dot = 0.0f;
      #pragma unroll
      for (int c=0;c<64;c+=4){
        float4 v = *(const float4*)&sj[j*64+c];
        dot = fmaf(xi[c+0],v.x,dot); dot = fmaf(xi[c+1],v.y,dot);
        dot = fmaf(xi[c+2],v.z,dot); dot = fmaf(xi[c+3],v.w,dot);
      }
      float d2 = (sqi + ssq[j]) - 2.0f*dot;
      if (d2 <= thr && cnt < SCAP){
        float2 e; e.x = d2; e.y = __int_as_float(jb + j);
        mybuf[cnt] = e;
        cnt++;
      }
    }
  }
  cnt4[(size_t)n*4 + jc] = cnt;
}

// ---------------- knn2 phase C: replay survivors into seed list ----------------
__global__ void knn2_select(const float* __restrict__ seed_d, const int* __restrict__ seed_i,
    const float2* __restrict__ surv, const int* __restrict__ cnt4,
    int* __restrict__ idx2){
  int n = blockIdx.x*256 + threadIdx.x;
  float bd[KNN]; int bi[KNN];
  #pragma unroll
  for (int s=0;s<KNN;++s){
    bd[s] = seed_d[(size_t)n*KNN + s];
    bi[s] = seed_i[(size_t)n*KNN + s];
  }
  #pragma unroll 1
  for (int c=0;c<4;++c){
    int nc = cnt4[(size_t)n*4 + c];
    const float2* buf = surv + ((size_t)n*4 + c)*SCAP;
    #pragma unroll 1
    for (int k=0;k<nc;++k){
      float2 e = buf[k];
      float d = e.x; int j = __float_as_int(e.y);
      if (d < bd[KNN-1]){
        TOP10_INSERT(d, j, bd, bi);
      }
    }
  }
  #pragma unroll
  for (int s=0;s<KNN;++s) idx2[(size_t)n*KNN+s] = bi[s];
}

// ---------------- q/r GEMM for edgeconv2: q=x1*Wbot, r=x1*(Wtop-Wbot)+b ----------------
__global__ __launch_bounds__(256,1) void qr2_kernel(const float* __restrict__ x1,
    const float* __restrict__ wcombg, const float* __restrict__ b2,
    float* __restrict__ q2, float* __restrict__ r2){
  __shared__ alignas(16) float sw[16384];    // 64 KB
  __shared__ float sb2[128];
  int t = threadIdx.x;
  for (int u=t; u<4096; u+=256) ((float4*)sw)[u] = ((const float4*)wcombg)[u];
  if (t < 128) sb2[t] = b2[t];
  __syncthreads();
  int n = blockIdx.x*256 + t;
  float xi[64];
  #pragma unroll
  for (int c=0;c<64;c+=4){
    float4 v = *(const float4*)&x1[(size_t)n*64+c];
    xi[c]=v.x; xi[c+1]=v.y; xi[c+2]=v.z; xi[c+3]=v.w;
  }
  #pragma unroll 1
  for (int op=0; op<128; op+=4){
    float q0=0,q1=0,q2a=0,q3=0, r0,r1,r2a,r3;
    r0=sb2[op]; r1=sb2[op+1]; r2a=sb2[op+2]; r3=sb2[op+3];
    #pragma unroll
    for (int c=0;c<64;c+=4){
      float4 a0 = *(const float4*)&sw[(op+0)*64+c];
      float4 a1 = *(const float4*)&sw[(op+1)*64+c];
      float4 a2 = *(const float4*)&sw[(op+2)*64+c];
      float4 a3 = *(const float4*)&sw[(op+3)*64+c];
      float4 c0 = *(const float4*)&sw[(128+op+0)*64+c];
      float4 c1 = *(const float4*)&sw[(128+op+1)*64+c];
      float4 c2 = *(const float4*)&sw[(128+op+2)*64+c];
      float4 c3 = *(const float4*)&sw[(128+op+3)*64+c];
      q0=fmaf(xi[c],a0.x,q0); q0=fmaf(xi[c+1],a0.y,q0); q0=fmaf(xi[c+2],a0.z,q0); q0=fmaf(xi[c+3],a0.w,q0);
      q1=fmaf(xi[c],a1.x,q1); q1=fmaf(xi[c+1],a1.y,q1); q1=fmaf(xi[c+2],a1.z,q1); q1=fmaf(xi[c+3],a1.w,q1);
      q2a=fmaf(xi[c],a2.x,q2a); q2a=fmaf(xi[c+1],a2.y,q2a); q2a=fmaf(xi[c+2],a2.z,q2a); q2a=fmaf(xi[c+3],a2.w,q2a);
      q3=fmaf(xi[c],a3.x,q3); q3=fmaf(xi[c+1],a3.y,q3); q3=fmaf(xi[c+2],a3.z,q3); q3=fmaf(xi[c+3],a3.w,q3);
      r0=fmaf(xi[c],c0.x,r0); r0=fmaf(xi[c+1],c0.y,r0); r0=fmaf(xi[c+2],c0.z,r0); r0=fmaf(xi[c+3],c0.w,r0);
      r1=fmaf(xi[c],c1.x,r1); r1=fmaf(xi[c+1],c1.y,r1); r1=fmaf(xi[c+2],c1.z,r1); r1=fmaf(xi[c+3],c1.w,r1);
      r2a=fmaf(xi[c],c2.x,r2a); r2a=fmaf(xi[c+1],c2.y,r2a); r2a=fmaf(xi[c+2],c2.z,r2a); r2a=fmaf(xi[c+3],c2.w,r2a);
      r3=fmaf(xi[c],c3.x,r3); r3=fmaf(xi[c+1],c3.y,r3); r3=fmaf(xi[c+2],c3.z,r3); r3=fmaf(xi[c+3],c3.w,r3);
    }
    float4 qv; qv.x=q0; qv.y=q1; qv.z=q2a; qv.w=q3;
    float4 rv; rv.x=r0; rv.y=r1; rv.z=r2a; rv.w=r3;
    *(float4*)&q2[(size_t)n*128+op] = qv;
    *(float4*)&r2[(size_t)n*128+op] = rv;
  }
}

// ---------------- edgeconv2 gather + fused mean (never materialize x2) ----------------
__global__ __launch_bounds__(256,4) void ec2_gather_kernel(
    const float* __restrict__ q2, const float* __restrict__ r2,
    const int* __restrict__ idx2, float* __restrict__ fmean){
  __shared__ alignas(16) float4 red[256];
  int t = threadIdx.x;
  int b = blockIdx.x >> 7, blk = blockIdx.x & 127;
  int p = t >> 5, c4 = t & 31;
  int n = b*NP + blk*8 + p;
  float4 r = *(const float4*)&r2[(size_t)n*128 + c4*4];
  float4 acc; acc.x=0; acc.y=0; acc.z=0; acc.w=0;
  #pragma unroll 1
  for (int k=0;k<KNN;++k){
    int j = idx2[n*KNN+k];
    float4 qv = *(const float4*)&q2[((size_t)b*NP + j)*128 + c4*4];
    acc.x += lrelu(r.x+qv.x);
    acc.y += lrelu(r.y+qv.y);
    acc.z += lrelu(r.z+qv.z);
    acc.w += lrelu(r.w+qv.w);
  }
  red[t] = acc;
  __syncthreads();
  if (t < 128){ float4 o = red[t+128]; red[t].x+=o.x; red[t].y+=o.y; red[t].z+=o.z; red[t].w+=o.w; }
  __syncthreads();
  if (t < 64){ float4 o = red[t+64]; red[t].x+=o.x; red[t].y+=o.y; red[t].z+=o.z; red[t].w+=o.w; }
  __syncthreads();
  if (t < 32){
    float4 s = red[t]; float4 o = red[t+32];
    s.x+=o.x; s.y+=o.y; s.z+=o.z; s.w+=o.w;
    float* dst = &fmean[b*192 + 64 + c4*4];
    atomicAdd(dst+0, s.x); atomicAdd(dst+1, s.y);
    atomicAdd(dst+2, s.z); atomicAdd(dst+3, s.w);
  }
}

// ---------------- mean of x1 -> fmean[:,0:64] (sums; /1024 applied in head) ----------------
__global__ __launch_bounds__(256,4) void mean1_kernel(const float* __restrict__ x1,
                                                      float* __restrict__ fmean){
  __shared__ float red[256];
  int t = threadIdx.x;
  int b = blockIdx.x >> 2, qq = blockIdx.x & 3;
  int c = t & 63, pl = t >> 6;
  float s = 0.0f;
  for (int i=0;i<64;++i){
    int p = qq*256 + pl + 4*i;
    s += x1[((size_t)b*NP + p)*64 + c];
  }
  red[t] = s;
  __syncthreads();
  if (t < 128) red[t] += red[t+128];
  __syncthreads();
  if (t < 64) atomicAdd(&fmean[b*192 + c], red[t] + red[t+64]);
}

// ---------------- head, split for parallelism ----------------
__global__ __launch_bounds__(256) void headA_kernel(const float* __restrict__ fmean,
    const float* __restrict__ wl, const float* __restrict__ bl,
    float* __restrict__ o1g){
  __shared__ float v0[192];
  int b = blockIdx.x >> 2, ch = blockIdx.x & 3, t = threadIdx.x;
  if (t < 192) v0[t] = fmean[b*192 + t] * (1.0f/1024.0f);
  __syncthreads();
  int o = ch*256 + t;
  float s = bl[o];
  #pragma unroll 8
  for (int c=0;c<192;++c) s = fmaf(v0[c], wl[c*1024 + o], s);
  o1g[b*1024 + o] = s;
}

__global__ __launch_bounds__(256) void headB_kernel(const float* __restrict__ o1g,
    const float* __restrict__ wm1, const float* __restrict__ bm1,
    float* __restrict__ h1g){
  __shared__ alignas(16) float vo[1024];
  int b = blockIdx.x >> 1, ch = blockIdx.x & 1, t = threadIdx.x;
  ((float4*)vo)[t] = ((const float4*)(o1g + b*1024))[t];
  __syncthreads();
  int o = ch*256 + t;
  float s = bm1[o];
  #pragma unroll 8
  for (int c=0;c<1024;++c) s = fmaf(vo[c], wm1[c*512 + o], s);
  h1g[b*512 + o] = lrelu(s);
}

__global__ __launch_bounds__(256) void headC_kernel(const float* __restrict__ h1g,
    const float* __restrict__ wm2, const float* __restrict__ bm2,
    const float* __restrict__ wm3, const float* __restrict__ bm3,
    float* __restrict__ out){
  __shared__ alignas(16) float vh[512];
  __shared__ float h2[256];
  int b = blockIdx.x, t = threadIdx.x;
  ((float2*)vh)[t] = ((const float2*)(h1g + b*512))[t];
  __syncthreads();
  float s = bm2[t];
  #pragma unroll 8
  for (int c=0;c<512;++c) s = fmaf(vh[c], wm2[c*256 + t], s);
  h2[t] = lrelu(s);
  __syncthreads();
  if (t < 3){
    float s2 = bm3[t];
    #pragma unroll 8
    for (int c=0;c<256;++c) s2 = fmaf(h2[c], wm3[c*3 + t], s2);
    out[b*3 + t] = s2;
  }
}

extern "C" void kernel_launch(void* const* d_in, const int* in_sizes, int n_in,
                              void* d_out, int out_size, void* d_ws, size_t ws_size,
                              hipStream_t stream) {
  const float* x   = (const float*)d_in[0];
  const float* pos = (const float*)d_in[1];
  const float* w1a = (const float*)d_in[3];
  const float* b1a = (const float*)d_in[4];
  const float* w1b = (const float*)d_in[5];
  const float* b1b = (const float*)d_in[6];
  const float* w1c = (const float*)d_in[7];
  const float* b1c = (const float*)d_in[8];
  const float* w2  = (const float*)d_in[9];
  const float* b2  = (const float*)d_in[10];
  const float* wl  = (const float*)d_in[11];
  const float* bl  = (const float*)d_in[12];
  const float* wm1 = (const float*)d_in[13];
  const float* bm1 = (const float*)d_in[14];
  const float* wm2 = (const float*)d_in[15];
  const float* bm2 = (const float*)d_in[16];
  const float* wm3 = (const float*)d_in[17];
  const float* bm3 = (const float*)d_in[18];
  float* out = (float*)d_out;

  float* ws_f  = (float*)d_ws;
  float* xx    = ws_f;                    // 262144 f
  float* x1    = xx + 262144;             // 4194304 f (16 MB)
  float* sq2   = x1 + 4194304;            // 65536 f
  int*   idx1  = (int*)(sq2 + 65536);     // 655360 i
  int*   idx2  = idx1 + 655360;           // 655360 i
  float* q2    = (float*)(idx2 + 655360); // 8388608 f (32 MB)
  float* r2    = q2 + 8388608;            // 8388608 f (32 MB)
  float* wcomb = r2 + 8388608;            // 16384 f
  float* fmean = wcomb + 16384;           // 12288 f
  float* o1g   = fmean + 12288;           // 65536 f
  float* h1g   = o1g + 65536;             // 32768 f
  float* seedd = h1g + 32768;             // 655360 f
  int*   seedi = (int*)(seedd + 655360);  // 655360 i
  float* Tbuf  = (float*)(seedi + 655360);// 65536 f
  int*   cnt4  = (int*)(Tbuf + 65536);    // 262144 i
  // Temporal overlays:
  //  q1/r1 on q2 region: written by qr1, read by edgeconv1, then clobbered by surv.
  //  bdh1/bih1 on r2 region: written by knn1, consumed by merge4 (before edgeconv1... 
  //  r2 region is separate from q2 -> no conflict with q1/r1).
  //  surv on q2 region (spills into r2): written by knn2_scan (after edgeconv1),
  //  consumed by knn2_select (before qr2 writes q2/r2).
  float* q1v   = q2;                      // 4194304 f
  float* r1v   = q2 + 4194304;            // 4194304 f
  float* bdh1  = r2;                      // 2621440 f
  int*   bih1  = (int*)(r2 + 2621440);    // 2621440 i
  float2* surv = (float2*)q2;             // 65536*4*30*8B

  prep_fused<<<368, 256, 0, stream>>>(x, pos, w2, xx, wcomb, fmean);
  qr1_kernel<<<256, 256, 0, stream>>>(xx, w1a, b1a, q1v, r1v);
  knn1_kernel<<<1024, 256, 0, stream>>>(xx, bdh1, bih1);
  merge4_kernel<<<256, 256, 0, stream>>>(bdh1, bih1, idx1);
  edgeconv1_kernel<<<512, 256, 0, stream>>>(q1v, r1v, idx1, w1b, b1b, w1c, b1c, x1, sq2);
  knn2_thresh<<<256, 256, 0, stream>>>(x1, sq2, seedd, seedi, Tbuf);
  knn2_scan<<<1024, 256, 0, stream>>>(x1, sq2, Tbuf, surv, cnt4);
  knn2_select<<<256, 256, 0, stream>>>(seedd, seedi, surv, cnt4, idx2);
  qr2_kernel<<<256, 256, 0, stream>>>(x1, wcomb, b2, q2, r2);
  ec2_gather_kernel<<<8192, 256, 0, stream>>>(q2, r2, idx2, fmean);
  mean1_kernel<<<256, 256, 0, stream>>>(x1, fmean);
  headA_kernel<<<256, 256, 0, stream>>>(fmean, wl, bl, o1g);
  headB_kernel<<<128, 256, 0, stream>>>(o1g, wm1, bm1, h1g);
  headC_kernel<<<64, 256, 0, stream>>>(h1g, wm2, bm2, wm3, bm3, out);
}

// Round 12
// 7350.740 us; speedup vs baseline: 1.1257x; 1.1257x over previous
//
#include <hip/hip_runtime.h>
#include <float.h>

#define NB 64
#define NP 1024
#define KNN 10
#define SCAP 30   // survivors per (point, j-chunk)

__device__ __forceinline__ float lrelu(float v){ return v >= 0.0f ? v : 0.01f*v; }

// sorted-ascending bubble insert; strict < keeps earlier-inserted (lower j) on ties.
// Only static data flow (no runtime-indexed register arrays — R6 spill lesson).
#define TOP10_INSERT(dk_, ik_, bd_, bi_)              \
  { float dk=dk_; int ik=ik_;                         \
    _Pragma("unroll")                                 \
    for (int s=0;s<KNN;++s){                          \
      bool sw = dk < bd_[s];                          \
      float td=bd_[s]; int ti=bi_[s];                 \
      bd_[s]=sw?dk:td; bi_[s]=sw?ik:ti;               \
      dk=sw?td:dk;     ik=sw?ti:ik; } }

// ---------------- fused prep: build xx, wcomb, zero fmean ----------------
__global__ void prep_fused(const float* __restrict__ x, const float* __restrict__ pos,
                           const float* __restrict__ w2,
                           float* __restrict__ xx, float* __restrict__ wcomb,
                           float* __restrict__ fmean){
  int tid = blockIdx.x*256 + threadIdx.x;   // grid 368 -> 94208 threads
  if (tid < 65536){
    float4 v;
    v.x = x[tid];
    v.y = pos[3*tid+0];
    v.z = pos[3*tid+1];
    v.w = pos[3*tid+2];
    ((float4*)xx)[tid] = v;
  } else if (tid < 65536+16384){
    int i = tid - 65536;
    int op = i >> 6, c = i & 63;
    if (op < 128){
      wcomb[i] = w2[(64+c)*128 + op];
    } else {
      int o = op - 128;
      wcomb[i] = w2[c*128 + o] - w2[(64+c)*128 + o];
    }
  } else {
    int i = tid - 65536 - 16384;
    if (i < NB*192) fmean[i] = 0.0f;
  }
}

// ---------------- qr1: q1 = xx@Wbot, r1 = xx@(Wtop-Wbot)+b1a ----------------
// w1a is (8,64): rows 0..3 = Wtop (xi part), rows 4..7 = Wbot (xj-xi part).
__global__ __launch_bounds__(256,4) void qr1_kernel(const float* __restrict__ xx,
    const float* __restrict__ w1a, const float* __restrict__ b1a,
    float* __restrict__ q1, float* __restrict__ r1){
  __shared__ alignas(16) float swt[256];  // Wtop-Wbot
  __shared__ alignas(16) float swb[256];  // Wbot
  __shared__ float sb[64];
  int t = threadIdx.x;
  {
    float top = w1a[t];
    float bot = w1a[256 + t];
    swb[t] = bot;
    swt[t] = top - bot;
  }
  if (t < 64) sb[t] = b1a[t];
  __syncthreads();
  int n = blockIdx.x*256 + t;
  float4 fi = ((const float4*)xx)[n];
  #pragma unroll 2
  for (int o=0;o<64;o+=4){
    float4 q, r;
    {
      float4 w0 = *(const float4*)&swb[0*64+o];
      float4 w1 = *(const float4*)&swb[1*64+o];
      float4 w2v = *(const float4*)&swb[2*64+o];
      float4 w3 = *(const float4*)&swb[3*64+o];
      q.x = fmaf(fi.x,w0.x, fmaf(fi.y,w1.x, fmaf(fi.z,w2v.x, fi.w*w3.x)));
      q.y = fmaf(fi.x,w0.y, fmaf(fi.y,w1.y, fmaf(fi.z,w2v.y, fi.w*w3.y)));
      q.z = fmaf(fi.x,w0.z, fmaf(fi.y,w1.z, fmaf(fi.z,w2v.z, fi.w*w3.z)));
      q.w = fmaf(fi.x,w0.w, fmaf(fi.y,w1.w, fmaf(fi.z,w2v.w, fi.w*w3.w)));
    }
    {
      float4 w0 = *(const float4*)&swt[0*64+o];
      float4 w1 = *(const float4*)&swt[1*64+o];
      float4 w2v = *(const float4*)&swt[2*64+o];
      float4 w3 = *(const float4*)&swt[3*64+o];
      r.x = sb[o+0] + fmaf(fi.x,w0.x, fmaf(fi.y,w1.x, fmaf(fi.z,w2v.x, fi.w*w3.x)));
      r.y = sb[o+1] + fmaf(fi.x,w0.y, fmaf(fi.y,w1.y, fmaf(fi.z,w2v.y, fi.w*w3.y)));
      r.z = sb[o+2] + fmaf(fi.x,w0.z, fmaf(fi.y,w1.z, fmaf(fi.z,w2v.z, fi.w*w3.z)));
      r.w = sb[o+3] + fmaf(fi.x,w0.w, fmaf(fi.y,w1.w, fmaf(fi.z,w2v.w, fi.w*w3.w)));
    }
    *(float4*)&q1[(size_t)n*64+o] = q;
    *(float4*)&r1[(size_t)n*64+o] = r;
  }
}

// ---------------- knn1: 4-dim features, 4 i-quarters x 4 j-quarters ----------------
__global__ __launch_bounds__(256,2) void knn1_kernel(const float* __restrict__ xx,
                                                     float* __restrict__ bdh1,
                                                     int* __restrict__ bih1){
  __shared__ alignas(16) float sf[256*4];   // 4 KB j-quarter points
  __shared__ float ssq[256];
  int bid = blockIdx.x;        // 1024 = 64 b x 4 iq x 4 jq
  int b  = bid >> 4;
  int iq = (bid >> 2) & 3;
  int jq = bid & 3;
  int t = threadIdx.x;
  {
    float4 v = ((const float4*)xx)[(size_t)b*NP + jq*256 + t];
    ((float4*)sf)[t] = v;
    ssq[t] = ((v.x*v.x + v.y*v.y) + v.z*v.z) + v.w*v.w;
  }
  __syncthreads();
  int il = iq*256 + t;
  int n = b*NP + il;
  float4 fi = ((const float4*)xx)[n];
  float sqi = ((fi.x*fi.x + fi.y*fi.y) + fi.z*fi.z) + fi.w*fi.w;
  float bd[KNN]; int bi[KNN];
  #pragma unroll
  for (int s=0;s<KNN;++s){ bd[s]=FLT_MAX; bi[s]=0; }
  #pragma unroll 1
  for (int j=0;j<256;++j){
    float4 fj = ((float4*)sf)[j];
    float dot = fi.x*fj.x + fi.y*fj.y + fi.z*fj.z + fi.w*fj.w;
    float d2 = (sqi + ssq[j]) - 2.0f*dot;
    if (d2 < bd[KNN-1]){
      TOP10_INSERT(d2, jq*256+j, bd, bi);
    }
  }
  #pragma unroll
  for (int s=0;s<KNN;++s){
    bdh1[((size_t)n*4 + jq)*KNN + s] = bd[s];
    bih1[((size_t)n*4 + jq)*KNN + s] = bi[s];
  }
}

// ---------------- fold-merge of 4 sorted lists (ties -> lower list = lower j) ----------------
__global__ void merge4_kernel(const float* __restrict__ bdh, const int* __restrict__ bih,
                              int* __restrict__ idx){
  int n = blockIdx.x*256 + threadIdx.x;
  float A[KNN]; int Ai[KNN];
  #pragma unroll
  for (int s=0;s<KNN;++s){
    A[s]  = bdh[(size_t)n*4*KNN + s];
    Ai[s] = bih[(size_t)n*4*KNN + s];
  }
  #pragma unroll
  for (int q=1;q<4;++q){
    float T[KNN]; int Ti[KNN];
    #pragma unroll
    for (int s=0;s<KNN;++s){
      T[s]  = bdh[((size_t)n*4+q)*KNN + s];
      Ti[s] = bih[((size_t)n*4+q)*KNN + s];
    }
    float O[KNN]; int Oi[KNN];
    #pragma unroll
    for (int s=0;s<KNN;++s){
      bool ta = A[0] <= T[0];
      O[s]  = ta ? A[0]  : T[0];
      Oi[s] = ta ? Ai[0] : Ti[0];
      #pragma unroll
      for (int u=0;u<KNN-1;++u){
        A[u]  = ta ? A[u+1]  : A[u];
        Ai[u] = ta ? Ai[u+1] : Ai[u];
        T[u]  = ta ? T[u]    : T[u+1];
        Ti[u] = ta ? Ti[u]   : Ti[u+1];
      }
    }
    #pragma unroll
    for (int s=0;s<KNN;++s){ A[s]=O[s]; Ai[s]=Oi[s]; }
  }
  #pragma unroll
  for (int s=0;s<KNN;++s) idx[(size_t)n*KNN+s] = Ai[s];
}

// ---------------- edgeconv1: 4 threads/point, 16 outputs each, 2-edge batching ----------------
// Layer a factored out (h1 = lrelu(r_i + q_j), r/q from qr1_kernel).
// h-exchange across the point's 4 lanes via ds_bpermute (__shfl_xor, per-lane
// mask). Live set ~96 floats -> no spill (R11 lesson: stay under ~100).
// Each weight ds_read_b128 feeds 8 FMAs (2 edges x 4 outputs).
__global__ __launch_bounds__(256,1) void edgeconv1_kernel(
    const float* __restrict__ q1, const float* __restrict__ r1,
    const int* __restrict__ idx1,
    const float* __restrict__ w1b, const float* __restrict__ b1b,
    const float* __restrict__ w1c, const float* __restrict__ b1c,
    float* __restrict__ x1, float* __restrict__ sq2){
  __shared__ alignas(16) float swb[4096];    // 16 KB w1b [c][o]
  __shared__ alignas(16) float swc[4096];    // 16 KB w1c [c][o]
  __shared__ float sbb[64], sbc[64];
  int t = threadIdx.x;
  for (int i=t; i<1024; i+=256) ((float4*)swb)[i] = ((const float4*)w1b)[i];
  for (int i=t; i<1024; i+=256) ((float4*)swc)[i] = ((const float4*)w1c)[i];
  if (t < 64){ sbb[t]=b1b[t]; sbc[t]=b1c[t]; }
  __syncthreads();

  int p  = t >> 2;           // local point 0..63
  int q  = t & 3;            // channel quarter
  int cb = q*16;             // my channel base
  int b  = blockIdx.x >> 4;  // batch
  int g  = blockIdx.x & 15;  // point group
  int n  = b*NP + g*64 + p;

  float rr[16];
  {
    const float4* rp = (const float4*)(r1 + (size_t)n*64 + cb);
    #pragma unroll
    for (int c4=0;c4<4;++c4){
      float4 v = rp[c4];
      rr[c4*4+0]=v.x; rr[c4*4+1]=v.y; rr[c4*4+2]=v.z; rr[c4*4+3]=v.w;
    }
  }
  float acc[16];
  #pragma unroll
  for (int o=0;o<16;++o) acc[o]=0.0f;

  #pragma unroll 1
  for (int kp=0; kp<5; ++kp){
    int j0 = idx1[n*KNN + kp*2];
    int j1 = idx1[n*KNN + kp*2 + 1];

    float h0[16], h1v[16];
    {
      const float4* q0p = (const float4*)(q1 + ((size_t)(b*NP) + j0)*64 + cb);
      const float4* q1p = (const float4*)(q1 + ((size_t)(b*NP) + j1)*64 + cb);
      #pragma unroll
      for (int c4=0;c4<4;++c4){
        float4 a0 = q0p[c4];
        float4 a1 = q1p[c4];
        h0[c4*4+0]=lrelu(rr[c4*4+0]+a0.x); h0[c4*4+1]=lrelu(rr[c4*4+1]+a0.y);
        h0[c4*4+2]=lrelu(rr[c4*4+2]+a0.z); h0[c4*4+3]=lrelu(rr[c4*4+3]+a0.w);
        h1v[c4*4+0]=lrelu(rr[c4*4+0]+a1.x); h1v[c4*4+1]=lrelu(rr[c4*4+1]+a1.y);
        h1v[c4*4+2]=lrelu(rr[c4*4+2]+a1.z); h1v[c4*4+3]=lrelu(rr[c4*4+3]+a1.w);
      }
    }

    // ---- layer b ----
    float pr0[16], pr1[16];
    #pragma unroll
    for (int o=0;o<16;++o){ float bb=sbb[cb+o]; pr0[o]=bb; pr1[o]=bb; }
    #pragma unroll
    for (int cq=0;cq<4;++cq){
      int m = q ^ cq;   // per-lane bpermute mask
      #pragma unroll
      for (int c=0;c<16;++c){
        float hv0 = __shfl_xor(h0[c],  m);
        float hv1 = __shfl_xor(h1v[c], m);
        int cg = cq*16 + c;
        #pragma unroll
        for (int o4=0;o4<4;++o4){
          float4 w = *(const float4*)&swb[cg*64 + cb + o4*4];
          pr0[o4*4+0]=fmaf(hv0,w.x,pr0[o4*4+0]);
          pr0[o4*4+1]=fmaf(hv0,w.y,pr0[o4*4+1]);
          pr0[o4*4+2]=fmaf(hv0,w.z,pr0[o4*4+2]);
          pr0[o4*4+3]=fmaf(hv0,w.w,pr0[o4*4+3]);
          pr1[o4*4+0]=fmaf(hv1,w.x,pr1[o4*4+0]);
          pr1[o4*4+1]=fmaf(hv1,w.y,pr1[o4*4+1]);
          pr1[o4*4+2]=fmaf(hv1,w.z,pr1[o4*4+2]);
          pr1[o4*4+3]=fmaf(hv1,w.w,pr1[o4*4+3]);
        }
      }
    }
    #pragma unroll
    for (int o=0;o<16;++o){ h0[o]=lrelu(pr0[o]); h1v[o]=lrelu(pr1[o]); }

    // ---- layer c ----
    #pragma unroll
    for (int o=0;o<16;++o){ float bb=sbc[cb+o]; pr0[o]=bb; pr1[o]=bb; }
    #pragma unroll
    for (int cq=0;cq<4;++cq){
      int m = q ^ cq;
      #pragma unroll
      for (int c=0;c<16;++c){
        float hv0 = __shfl_xor(h0[c],  m);
        float hv1 = __shfl_xor(h1v[c], m);
        int cg = cq*16 + c;
        #pragma unroll
        for (int o4=0;o4<4;++o4){
          float4 w = *(const float4*)&swc[cg*64 + cb + o4*4];
          pr0[o4*4+0]=fmaf(hv0,w.x,pr0[o4*4+0]);
          pr0[o4*4+1]=fmaf(hv0,w.y,pr0[o4*4+1]);
          pr0[o4*4+2]=fmaf(hv0,w.z,pr0[o4*4+2]);
          pr0[o4*4+3]=fmaf(hv0,w.w,pr0[o4*4+3]);
          pr1[o4*4+0]=fmaf(hv1,w.x,pr1[o4*4+0]);
          pr1[o4*4+1]=fmaf(hv1,w.y,pr1[o4*4+1]);
          pr1[o4*4+2]=fmaf(hv1,w.z,pr1[o4*4+2]);
          pr1[o4*4+3]=fmaf(hv1,w.w,pr1[o4*4+3]);
        }
      }
    }
    #pragma unroll
    for (int o=0;o<16;++o) acc[o] += lrelu(pr0[o]) + lrelu(pr1[o]);
  }

  float s = 0.0f;
  #pragma unroll
  for (int o=0;o<16;o+=4){
    float4 v; v.x=acc[o]; v.y=acc[o+1]; v.z=acc[o+2]; v.w=acc[o+3];
    *(float4*)&x1[(size_t)n*64 + cb + o] = v;
    s = fmaf(acc[o],acc[o], fmaf(acc[o+1],acc[o+1], fmaf(acc[o+2],acc[o+2], fmaf(acc[o+3],acc[o+3], s))));
  }
  s += __shfl_xor(s, 1);
  s += __shfl_xor(s, 2);
  if (q == 0) sq2[n] = s;
}

// ---------------- knn2 phase A: exact top-10 over j in [0,256) + threshold ----------------
__global__ __launch_bounds__(256,1) void knn2_thresh(const float* __restrict__ x1,
    const float* __restrict__ sq2,
    float* __restrict__ seed_d, int* __restrict__ seed_i, float* __restrict__ Tout){
  __shared__ alignas(16) float sj[64*64];    // 16 KB
  __shared__ float ssq[64];
  int b  = blockIdx.x >> 2;
  int ig = blockIdx.x & 3;
  int t = threadIdx.x;
  int n = b*NP + ig*256 + t;
  float xi[64];
  #pragma unroll
  for (int c=0;c<64;c+=4){
    float4 v = *(const float4*)&x1[(size_t)n*64+c];
    xi[c]=v.x; xi[c+1]=v.y; xi[c+2]=v.z; xi[c+3]=v.w;
  }
  float sqi = sq2[n];
  float bd[KNN]; int bi[KNN];
  #pragma unroll
  for (int s=0;s<KNN;++s){ bd[s]=FLT_MAX; bi[s]=0; }
  for (int tile=0; tile<4; ++tile){
    __syncthreads();
    const float4* src = (const float4*)(x1 + ((size_t)b*NP + tile*64)*64);
    for (int u=t; u<1024; u+=256) ((float4*)sj)[u] = src[u];
    if (t < 64) ssq[t] = sq2[b*NP + tile*64 + t];
    __syncthreads();
    #pragma unroll 1
    for (int j=0;j<64;++j){
      float dot = 0.0f;
      #pragma unroll
      for (int c=0;c<64;c+=4){
        float4 v = *(const float4*)&sj[j*64+c];
        dot = fmaf(xi[c+0],v.x,dot); dot = fmaf(xi[c+1],v.y,dot);
        dot = fmaf(xi[c+2],v.z,dot); dot = fmaf(xi[c+3],v.w,dot);
      }
      float d2 = (sqi + ssq[j]) - 2.0f*dot;
      if (d2 < bd[KNN-1]){
        TOP10_INSERT(d2, tile*64+j, bd, bi);
      }
    }
  }
  #pragma unroll
  for (int s=0;s<KNN;++s){
    seed_d[(size_t)n*KNN + s] = bd[s];
    seed_i[(size_t)n*KNN + s] = bi[s];
  }
  Tout[n] = bd[KNN-1];
}

// ---------------- knn2 phase B: filtered scan of j in [256,1024), 4 chunks ----------------
__global__ __launch_bounds__(256,2) void knn2_scan(const float* __restrict__ x1,
    const float* __restrict__ sq2, const float* __restrict__ Tin,
    float2* __restrict__ surv, int* __restrict__ cnt4){
  __shared__ alignas(16) float sj[96*64];    // 24 KB
  __shared__ float ssq[96];
  int bid = blockIdx.x;     // 1024 = 64 b x 4 ig x 4 jc
  int b  = bid >> 4;
  int ig = (bid >> 2) & 3;
  int jc = bid & 3;
  int t = threadIdx.x;
  int n = b*NP + ig*256 + t;
  float xi[64];
  #pragma unroll
  for (int c=0;c<64;c+=4){
    float4 v = *(const float4*)&x1[(size_t)n*64+c];
    xi[c]=v.x; xi[c+1]=v.y; xi[c+2]=v.z; xi[c+3]=v.w;
  }
  float sqi = sq2[n];
  float thr = Tin[n];
  int cnt = 0;
  float2* mybuf = surv + ((size_t)n*4 + jc)*SCAP;
  int jbase0 = 256 + jc*192;
  for (int tile=0; tile<2; ++tile){
    int jb = jbase0 + tile*96;
    __syncthreads();
    const float4* src = (const float4*)(x1 + ((size_t)b*NP + jb)*64);
    for (int u=t; u<1536; u+=256) ((float4*)sj)[u] = src[u];
    if (t < 96) ssq[t] = sq2[b*NP + jb + t];
    __syncthreads();
    #pragma unroll 1
    for (int j=0;j<96;++j){
      float dot = 0.0f;
      #pragma unroll
      for (int c=0;c<64;c+=4){
        float4 v = *(const float4*)&sj[j*64+c];
        dot = fmaf(xi[c+0],v.x,dot); dot = fmaf(xi[c+1],v.y,dot);
        dot = fmaf(xi[c+2],v.z,dot); dot = fmaf(xi[c+3],v.w,dot);
      }
      float d2 = (sqi + ssq[j]) - 2.0f*dot;
      if (d2 <= thr && cnt < SCAP){
        float2 e; e.x = d2; e.y = __int_as_float(jb + j);
        mybuf[cnt] = e;
        cnt++;
      }
    }
  }
  cnt4[(size_t)n*4 + jc] = cnt;
}

// ---------------- knn2 phase C: replay survivors into seed list ----------------
__global__ void knn2_select(const float* __restrict__ seed_d, const int* __restrict__ seed_i,
    const float2* __restrict__ surv, const int* __restrict__ cnt4,
    int* __restrict__ idx2){
  int n = blockIdx.x*256 + threadIdx.x;
  float bd[KNN]; int bi[KNN];
  #pragma unroll
  for (int s=0;s<KNN;++s){
    bd[s] = seed_d[(size_t)n*KNN + s];
    bi[s] = seed_i[(size_t)n*KNN + s];
  }
  #pragma unroll 1
  for (int c=0;c<4;++c){
    int nc = cnt4[(size_t)n*4 + c];
    const float2* buf = surv + ((size_t)n*4 + c)*SCAP;
    #pragma unroll 1
    for (int k=0;k<nc;++k){
      float2 e = buf[k];
      float d = e.x; int j = __float_as_int(e.y);
      if (d < bd[KNN-1]){
        TOP10_INSERT(d, j, bd, bi);
      }
    }
  }
  #pragma unroll
  for (int s=0;s<KNN;++s) idx2[(size_t)n*KNN+s] = bi[s];
}

// ---------------- q/r GEMM for edgeconv2: q=x1*Wbot, r=x1*(Wtop-Wbot)+b ----------------
__global__ __launch_bounds__(256,1) void qr2_kernel(const float* __restrict__ x1,
    const float* __restrict__ wcombg, const float* __restrict__ b2,
    float* __restrict__ q2, float* __restrict__ r2){
  __shared__ alignas(16) float sw[16384];    // 64 KB
  __shared__ float sb2[128];
  int t = threadIdx.x;
  for (int u=t; u<4096; u+=256) ((float4*)sw)[u] = ((const float4*)wcombg)[u];
  if (t < 128) sb2[t] = b2[t];
  __syncthreads();
  int n = blockIdx.x*256 + t;
  float xi[64];
  #pragma unroll
  for (int c=0;c<64;c+=4){
    float4 v = *(const float4*)&x1[(size_t)n*64+c];
    xi[c]=v.x; xi[c+1]=v.y; xi[c+2]=v.z; xi[c+3]=v.w;
  }
  #pragma unroll 1
  for (int op=0; op<128; op+=4){
    float q0=0,q1=0,q2a=0,q3=0, r0,r1,r2a,r3;
    r0=sb2[op]; r1=sb2[op+1]; r2a=sb2[op+2]; r3=sb2[op+3];
    #pragma unroll
    for (int c=0;c<64;c+=4){
      float4 a0 = *(const float4*)&sw[(op+0)*64+c];
      float4 a1 = *(const float4*)&sw[(op+1)*64+c];
      float4 a2 = *(const float4*)&sw[(op+2)*64+c];
      float4 a3 = *(const float4*)&sw[(op+3)*64+c];
      float4 c0 = *(const float4*)&sw[(128+op+0)*64+c];
      float4 c1 = *(const float4*)&sw[(128+op+1)*64+c];
      float4 c2 = *(const float4*)&sw[(128+op+2)*64+c];
      float4 c3 = *(const float4*)&sw[(128+op+3)*64+c];
      q0=fmaf(xi[c],a0.x,q0); q0=fmaf(xi[c+1],a0.y,q0); q0=fmaf(xi[c+2],a0.z,q0); q0=fmaf(xi[c+3],a0.w,q0);
      q1=fmaf(xi[c],a1.x,q1); q1=fmaf(xi[c+1],a1.y,q1); q1=fmaf(xi[c+2],a1.z,q1); q1=fmaf(xi[c+3],a1.w,q1);
      q2a=fmaf(xi[c],a2.x,q2a); q2a=fmaf(xi[c+1],a2.y,q2a); q2a=fmaf(xi[c+2],a2.z,q2a); q2a=fmaf(xi[c+3],a2.w,q2a);
      q3=fmaf(xi[c],a3.x,q3); q3=fmaf(xi[c+1],a3.y,q3); q3=fmaf(xi[c+2],a3.z,q3); q3=fmaf(xi[c+3],a3.w,q3);
      r0=fmaf(xi[c],c0.x,r0); r0=fmaf(xi[c+1],c0.y,r0); r0=fmaf(xi[c+2],c0.z,r0); r0=fmaf(xi[c+3],c0.w,r0);
      r1=fmaf(xi[c],c1.x,r1); r1=fmaf(xi[c+1],c1.y,r1); r1=fmaf(xi[c+2],c1.z,r1); r1=fmaf(xi[c+3],c1.w,r1);
      r2a=fmaf(xi[c],c2.x,r2a); r2a=fmaf(xi[c+1],c2.y,r2a); r2a=fmaf(xi[c+2],c2.z,r2a); r2a=fmaf(xi[c+3],c2.w,r2a);
      r3=fmaf(xi[c],c3.x,r3); r3=fmaf(xi[c+1],c3.y,r3); r3=fmaf(xi[c+2],c3.z,r3); r3=fmaf(xi[c+3],c3.w,r3);
    }
    float4 qv; qv.x=q0; qv.y=q1; qv.z=q2a; qv.w=q3;
    float4 rv; rv.x=r0; rv.y=r1; rv.z=r2a; rv.w=r3;
    *(float4*)&q2[(size_t)n*128+op] = qv;
    *(float4*)&r2[(size_t)n*128+op] = rv;
  }
}

// ---------------- edgeconv2 gather + fused mean (never materialize x2) ----------------
__global__ __launch_bounds__(256,4) void ec2_gather_kernel(
    const float* __restrict__ q2, const float* __restrict__ r2,
    const int* __restrict__ idx2, float* __restrict__ fmean){
  __shared__ alignas(16) float4 red[256];
  int t = threadIdx.x;
  int b = blockIdx.x >> 7, blk = blockIdx.x & 127;
  int p = t >> 5, c4 = t & 31;
  int n = b*NP + blk*8 + p;
  float4 r = *(const float4*)&r2[(size_t)n*128 + c4*4];
  float4 acc; acc.x=0; acc.y=0; acc.z=0; acc.w=0;
  #pragma unroll 1
  for (int k=0;k<KNN;++k){
    int j = idx2[n*KNN+k];
    float4 qv = *(const float4*)&q2[((size_t)b*NP + j)*128 + c4*4];
    acc.x += lrelu(r.x+qv.x);
    acc.y += lrelu(r.y+qv.y);
    acc.z += lrelu(r.z+qv.z);
    acc.w += lrelu(r.w+qv.w);
  }
  red[t] = acc;
  __syncthreads();
  if (t < 128){ float4 o = red[t+128]; red[t].x+=o.x; red[t].y+=o.y; red[t].z+=o.z; red[t].w+=o.w; }
  __syncthreads();
  if (t < 64){ float4 o = red[t+64]; red[t].x+=o.x; red[t].y+=o.y; red[t].z+=o.z; red[t].w+=o.w; }
  __syncthreads();
  if (t < 32){
    float4 s = red[t]; float4 o = red[t+32];
    s.x+=o.x; s.y+=o.y; s.z+=o.z; s.w+=o.w;
    float* dst = &fmean[b*192 + 64 + c4*4];
    atomicAdd(dst+0, s.x); atomicAdd(dst+1, s.y);
    atomicAdd(dst+2, s.z); atomicAdd(dst+3, s.w);
  }
}

// ---------------- mean of x1 -> fmean[:,0:64] (sums; /1024 applied in head) ----------------
__global__ __launch_bounds__(256,4) void mean1_kernel(const float* __restrict__ x1,
                                                      float* __restrict__ fmean){
  __shared__ float red[256];
  int t = threadIdx.x;
  int b = blockIdx.x >> 2, qq = blockIdx.x & 3;
  int c = t & 63, pl = t >> 6;
  float s = 0.0f;
  for (int i=0;i<64;++i){
    int p = qq*256 + pl + 4*i;
    s += x1[((size_t)b*NP + p)*64 + c];
  }
  red[t] = s;
  __syncthreads();
  if (t < 128) red[t] += red[t+128];
  __syncthreads();
  if (t < 64) atomicAdd(&fmean[b*192 + c], red[t] + red[t+64]);
}

// ---------------- head, split for parallelism ----------------
__global__ __launch_bounds__(256) void headA_kernel(const float* __restrict__ fmean,
    const float* __restrict__ wl, const float* __restrict__ bl,
    float* __restrict__ o1g){
  __shared__ float v0[192];
  int b = blockIdx.x >> 2, ch = blockIdx.x & 3, t = threadIdx.x;
  if (t < 192) v0[t] = fmean[b*192 + t] * (1.0f/1024.0f);
  __syncthreads();
  int o = ch*256 + t;
  float s = bl[o];
  #pragma unroll 8
  for (int c=0;c<192;++c) s = fmaf(v0[c], wl[c*1024 + o], s);
  o1g[b*1024 + o] = s;
}

__global__ __launch_bounds__(256) void headB_kernel(const float* __restrict__ o1g,
    const float* __restrict__ wm1, const float* __restrict__ bm1,
    float* __restrict__ h1g){
  __shared__ alignas(16) float vo[1024];
  int b = blockIdx.x >> 1, ch = blockIdx.x & 1, t = threadIdx.x;
  ((float4*)vo)[t] = ((const float4*)(o1g + b*1024))[t];
  __syncthreads();
  int o = ch*256 + t;
  float s = bm1[o];
  #pragma unroll 8
  for (int c=0;c<1024;++c) s = fmaf(vo[c], wm1[c*512 + o], s);
  h1g[b*512 + o] = lrelu(s);
}

__global__ __launch_bounds__(256) void headC_kernel(const float* __restrict__ h1g,
    const float* __restrict__ wm2, const float* __restrict__ bm2,
    const float* __restrict__ wm3, const float* __restrict__ bm3,
    float* __restrict__ out){
  __shared__ alignas(16) float vh[512];
  __shared__ float h2[256];
  int b = blockIdx.x, t = threadIdx.x;
  ((float2*)vh)[t] = ((const float2*)(h1g + b*512))[t];
  __syncthreads();
  float s = bm2[t];
  #pragma unroll 8
  for (int c=0;c<512;++c) s = fmaf(vh[c], wm2[c*256 + t], s);
  h2[t] = lrelu(s);
  __syncthreads();
  if (t < 3){
    float s2 = bm3[t];
    #pragma unroll 8
    for (int c=0;c<256;++c) s2 = fmaf(h2[c], wm3[c*3 + t], s2);
    out[b*3 + t] = s2;
  }
}

extern "C" void kernel_launch(void* const* d_in, const int* in_sizes, int n_in,
                              void* d_out, int out_size, void* d_ws, size_t ws_size,
                              hipStream_t stream) {
  const float* x   = (const float*)d_in[0];
  const float* pos = (const float*)d_in[1];
  const float* w1a = (const float*)d_in[3];
  const float* b1a = (const float*)d_in[4];
  const float* w1b = (const float*)d_in[5];
  const float* b1b = (const float*)d_in[6];
  const float* w1c = (const float*)d_in[7];
  const float* b1c = (const float*)d_in[8];
  const float* w2  = (const float*)d_in[9];
  const float* b2  = (const float*)d_in[10];
  const float* wl  = (const float*)d_in[11];
  const float* bl  = (const float*)d_in[12];
  const float* wm1 = (const float*)d_in[13];
  const float* bm1 = (const float*)d_in[14];
  const float* wm2 = (const float*)d_in[15];
  const float* bm2 = (const float*)d_in[16];
  const float* wm3 = (const float*)d_in[17];
  const float* bm3 = (const float*)d_in[18];
  float* out = (float*)d_out;

  float* ws_f  = (float*)d_ws;
  float* xx    = ws_f;                    // 262144 f
  float* x1    = xx + 262144;             // 4194304 f (16 MB)
  float* sq2   = x1 + 4194304;            // 65536 f
  int*   idx1  = (int*)(sq2 + 65536);     // 655360 i
  int*   idx2  = idx1 + 655360;           // 655360 i
  float* q2    = (float*)(idx2 + 655360); // 8388608 f (32 MB)
  float* r2    = q2 + 8388608;            // 8388608 f (32 MB)
  float* wcomb = r2 + 8388608;            // 16384 f
  float* fmean = wcomb + 16384;           // 12288 f
  float* o1g   = fmean + 12288;           // 65536 f
  float* h1g   = o1g + 65536;             // 32768 f
  float* seedd = h1g + 32768;             // 655360 f
  int*   seedi = (int*)(seedd + 655360);  // 655360 i
  float* Tbuf  = (float*)(seedi + 655360);// 65536 f
  int*   cnt4  = (int*)(Tbuf + 65536);    // 262144 i
  // Temporal overlays:
  //  q1/r1 on q2 region: written by qr1, read by edgeconv1, clobbered by surv after.
  //  bdh1/bih1 on r2 region: knn1 -> merge4, done before qr2 writes r2.
  //  surv on q2 region: knn2_scan (after edgeconv1) -> knn2_select (before qr2).
  float* q1v   = q2;                      // 4194304 f
  float* r1v   = q2 + 4194304;            // 4194304 f
  float* bdh1  = r2;                      // 2621440 f
  int*   bih1  = (int*)(r2 + 2621440);    // 2621440 i
  float2* surv = (float2*)q2;             // 65536*4*30*8B

  prep_fused<<<368, 256, 0, stream>>>(x, pos, w2, xx, wcomb, fmean);
  qr1_kernel<<<256, 256, 0, stream>>>(xx, w1a, b1a, q1v, r1v);
  knn1_kernel<<<1024, 256, 0, stream>>>(xx, bdh1, bih1);
  merge4_kernel<<<256, 256, 0, stream>>>(bdh1, bih1, idx1);
  edgeconv1_kernel<<<1024, 256, 0, stream>>>(q1v, r1v, idx1, w1b, b1b, w1c, b1c, x1, sq2);
  knn2_thresh<<<256, 256, 0, stream>>>(x1, sq2, seedd, seedi, Tbuf);
  knn2_scan<<<1024, 256, 0, stream>>>(x1, sq2, Tbuf, surv, cnt4);
  knn2_select<<<256, 256, 0, stream>>>(seedd, seedi, surv, cnt4, idx2);
  qr2_kernel<<<256, 256, 0, stream>>>(x1, wcomb, b2, q2, r2);
  ec2_gather_kernel<<<8192, 256, 0, stream>>>(q2, r2, idx2, fmean);
  mean1_kernel<<<256, 256, 0, stream>>>(x1, fmean);
  headA_kernel<<<256, 256, 0, stream>>>(fmean, wl, bl, o1g);
  headB_kernel<<<128, 256, 0, stream>>>(o1g, wm1, bm1, h1g);
  headC_kernel<<<64, 256, 0, stream>>>(h1g, wm2, bm2, wm3, bm3, out);
}

// Round 13
// 1041.196 us; speedup vs baseline: 7.9473x; 7.0599x over previous
//
#include <hip/hip_runtime.h>
#include <float.h>

#define NB 64
#define NP 1024
#define KNN 10
#define SCAP 30   // survivors per (point, j-chunk)

__device__ __forceinline__ float lrelu(float v){ return v >= 0.0f ? v : 0.01f*v; }

// sorted-ascending bubble insert; strict < keeps earlier-inserted (lower j) on ties.
// Only static data flow (no runtime-indexed register arrays — R6 spill lesson).
#define TOP10_INSERT(dk_, ik_, bd_, bi_)              \
  { float dk=dk_; int ik=ik_;                         \
    _Pragma("unroll")                                 \
    for (int s=0;s<KNN;++s){                          \
      bool sw = dk < bd_[s];                          \
      float td=bd_[s]; int ti=bi_[s];                 \
      bd_[s]=sw?dk:td; bi_[s]=sw?ik:ti;               \
      dk=sw?td:dk;     ik=sw?ti:ik; } }

// ---------------- fused prep: build xx, wcomb, zero fmean ----------------
__global__ void prep_fused(const float* __restrict__ x, const float* __restrict__ pos,
                           const float* __restrict__ w2,
                           float* __restrict__ xx, float* __restrict__ wcomb,
                           float* __restrict__ fmean){
  int tid = blockIdx.x*256 + threadIdx.x;   // grid 368 -> 94208 threads
  if (tid < 65536){
    float4 v;
    v.x = x[tid];
    v.y = pos[3*tid+0];
    v.z = pos[3*tid+1];
    v.w = pos[3*tid+2];
    ((float4*)xx)[tid] = v;
  } else if (tid < 65536+16384){
    int i = tid - 65536;
    int op = i >> 6, c = i & 63;
    if (op < 128){
      wcomb[i] = w2[(64+c)*128 + op];
    } else {
      int o = op - 128;
      wcomb[i] = w2[c*128 + o] - w2[(64+c)*128 + o];
    }
  } else {
    int i = tid - 65536 - 16384;
    if (i < NB*192) fmean[i] = 0.0f;
  }
}

// ---------------- knn1: 4-dim features, 4 i-quarters x 4 j-quarters ----------------
__global__ __launch_bounds__(256,2) void knn1_kernel(const float* __restrict__ xx,
                                                     float* __restrict__ bdh1,
                                                     int* __restrict__ bih1){
  __shared__ alignas(16) float sf[256*4];   // 4 KB j-quarter points
  __shared__ float ssq[256];
  int bid = blockIdx.x;        // 1024 = 64 b x 4 iq x 4 jq
  int b  = bid >> 4;
  int iq = (bid >> 2) & 3;
  int jq = bid & 3;
  int t = threadIdx.x;
  {
    float4 v = ((const float4*)xx)[(size_t)b*NP + jq*256 + t];
    ((float4*)sf)[t] = v;
    ssq[t] = ((v.x*v.x + v.y*v.y) + v.z*v.z) + v.w*v.w;
  }
  __syncthreads();
  int il = iq*256 + t;
  int n = b*NP + il;
  float4 fi = ((const float4*)xx)[n];
  float sqi = ((fi.x*fi.x + fi.y*fi.y) + fi.z*fi.z) + fi.w*fi.w;
  float bd[KNN]; int bi[KNN];
  #pragma unroll
  for (int s=0;s<KNN;++s){ bd[s]=FLT_MAX; bi[s]=0; }
  #pragma unroll 1
  for (int j=0;j<256;++j){
    float4 fj = ((float4*)sf)[j];
    float dot = fi.x*fj.x + fi.y*fj.y + fi.z*fj.z + fi.w*fj.w;
    float d2 = (sqi + ssq[j]) - 2.0f*dot;
    if (d2 < bd[KNN-1]){
      TOP10_INSERT(d2, jq*256+j, bd, bi);
    }
  }
  #pragma unroll
  for (int s=0;s<KNN;++s){
    bdh1[((size_t)n*4 + jq)*KNN + s] = bd[s];
    bih1[((size_t)n*4 + jq)*KNN + s] = bi[s];
  }
}

// ---------------- fold-merge of 4 sorted lists (ties -> lower list = lower j) ----------------
__global__ void merge4_kernel(const float* __restrict__ bdh, const int* __restrict__ bih,
                              int* __restrict__ idx){
  int n = blockIdx.x*256 + threadIdx.x;
  float A[KNN]; int Ai[KNN];
  #pragma unroll
  for (int s=0;s<KNN;++s){
    A[s]  = bdh[(size_t)n*4*KNN + s];
    Ai[s] = bih[(size_t)n*4*KNN + s];
  }
  #pragma unroll
  for (int q=1;q<4;++q){
    float T[KNN]; int Ti[KNN];
    #pragma unroll
    for (int s=0;s<KNN;++s){
      T[s]  = bdh[((size_t)n*4+q)*KNN + s];
      Ti[s] = bih[((size_t)n*4+q)*KNN + s];
    }
    float O[KNN]; int Oi[KNN];
    #pragma unroll
    for (int s=0;s<KNN;++s){
      bool ta = A[0] <= T[0];
      O[s]  = ta ? A[0]  : T[0];
      Oi[s] = ta ? Ai[0] : Ti[0];
      #pragma unroll
      for (int u=0;u<KNN-1;++u){
        A[u]  = ta ? A[u+1]  : A[u];
        Ai[u] = ta ? Ai[u+1] : Ai[u];
        T[u]  = ta ? T[u]    : T[u+1];
        Ti[u] = ta ? Ti[u]   : Ti[u+1];
      }
    }
    #pragma unroll
    for (int s=0;s<KNN;++s){ A[s]=O[s]; Ai[s]=Oi[s]; }
  }
  #pragma unroll
  for (int s=0;s<KNN;++s) idx[(size_t)n*KNN+s] = Ai[s];
}

// ---------------- edgeconv1: 2 threads per point, 32 outputs each (R10 proven) ----------------
__global__ __launch_bounds__(256,2) void edgeconv1_kernel(
    const float* __restrict__ xx, const int* __restrict__ idx1,
    const float* __restrict__ w1a, const float* __restrict__ b1a,
    const float* __restrict__ w1b, const float* __restrict__ b1b,
    const float* __restrict__ w1c, const float* __restrict__ b1c,
    float* __restrict__ x1, float* __restrict__ sq2){
  __shared__ alignas(16) float swa[512];     //  2 KB w1a [c][o]
  __shared__ alignas(16) float swb[4096];    // 16 KB w1b [c][o]
  __shared__ alignas(16) float swc[4096];    // 16 KB w1c [c][o]
  __shared__ float sba[64], sbb[64], sbc[64];
  __shared__ float hx[128*65];               // 33.3 KB per-point activation rows
  int t = threadIdx.x;
  for (int i=t; i<128;  i+=256) ((float4*)swa)[i] = ((const float4*)w1a)[i];
  for (int i=t; i<1024; i+=256) ((float4*)swb)[i] = ((const float4*)w1b)[i];
  for (int i=t; i<1024; i+=256) ((float4*)swc)[i] = ((const float4*)w1c)[i];
  if (t < 64){ sba[t]=b1a[t]; sbb[t]=b1b[t]; sbc[t]=b1c[t]; }
  __syncthreads();

  int p  = t >> 1;          // local point 0..127
  int hf = t & 1;           // output half
  int ob = hf*32;
  int b  = blockIdx.x >> 3; // batch
  int g  = blockIdx.x & 7;  // point group
  int n  = b*NP + g*128 + p;
  float* hrow = &hx[p*65];

  float4 fi = ((const float4*)xx)[n];
  float acc[32];
  #pragma unroll
  for (int o=0;o<32;++o) acc[o]=0.0f;

  #pragma unroll 1
  for (int k=0;k<KNN;++k){
    int j = idx1[n*KNN+k];
    float4 fj = ((const float4*)xx)[b*NP + j];
    float e[8];
    e[0]=fi.x; e[1]=fi.y; e[2]=fi.z; e[3]=fi.w;
    e[4]=fj.x-fi.x; e[5]=fj.y-fi.y; e[6]=fj.z-fi.z; e[7]=fj.w-fi.w;

    {
      float pr[32];
      #pragma unroll
      for (int o=0;o<32;++o) pr[o]=sba[ob+o];
      #pragma unroll
      for (int c=0;c<8;++c){
        #pragma unroll
        for (int o4=0;o4<8;++o4){
          float4 w = *(const float4*)&swa[c*64 + ob + o4*4];
          pr[o4*4+0]=fmaf(e[c],w.x,pr[o4*4+0]);
          pr[o4*4+1]=fmaf(e[c],w.y,pr[o4*4+1]);
          pr[o4*4+2]=fmaf(e[c],w.z,pr[o4*4+2]);
          pr[o4*4+3]=fmaf(e[c],w.w,pr[o4*4+3]);
        }
      }
      #pragma unroll
      for (int o=0;o<32;++o) hrow[ob+o] = lrelu(pr[o]);
    }
    __syncthreads();

    float h2v[32];
    {
      float pr[32];
      #pragma unroll
      for (int o=0;o<32;++o) pr[o]=sbb[ob+o];
      #pragma unroll 4
      for (int c=0;c<64;++c){
        float hv = hrow[c];
        #pragma unroll
        for (int o4=0;o4<8;++o4){
          float4 w = *(const float4*)&swb[c*64 + ob + o4*4];
          pr[o4*4+0]=fmaf(hv,w.x,pr[o4*4+0]);
          pr[o4*4+1]=fmaf(hv,w.y,pr[o4*4+1]);
          pr[o4*4+2]=fmaf(hv,w.z,pr[o4*4+2]);
          pr[o4*4+3]=fmaf(hv,w.w,pr[o4*4+3]);
        }
      }
      #pragma unroll
      for (int o=0;o<32;++o) h2v[o] = lrelu(pr[o]);
    }
    __syncthreads();
    #pragma unroll
    for (int o=0;o<32;++o) hrow[ob+o] = h2v[o];
    __syncthreads();

    {
      float pr[32];
      #pragma unroll
      for (int o=0;o<32;++o) pr[o]=sbc[ob+o];
      #pragma unroll 4
      for (int c=0;c<64;++c){
        float hv = hrow[c];
        #pragma unroll
        for (int o4=0;o4<8;++o4){
          float4 w = *(const float4*)&swc[c*64 + ob + o4*4];
          pr[o4*4+0]=fmaf(hv,w.x,pr[o4*4+0]);
          pr[o4*4+1]=fmaf(hv,w.y,pr[o4*4+1]);
          pr[o4*4+2]=fmaf(hv,w.z,pr[o4*4+2]);
          pr[o4*4+3]=fmaf(hv,w.w,pr[o4*4+3]);
        }
      }
      #pragma unroll
      for (int o=0;o<32;++o) acc[o] += lrelu(pr[o]);
    }
    __syncthreads();
  }

  float s = 0.0f;
  #pragma unroll
  for (int o=0;o<32;o+=4){
    float4 v; v.x=acc[o]; v.y=acc[o+1]; v.z=acc[o+2]; v.w=acc[o+3];
    *(float4*)&x1[(size_t)n*64 + ob + o] = v;
    s = fmaf(acc[o],acc[o], fmaf(acc[o+1],acc[o+1], fmaf(acc[o+2],acc[o+2], fmaf(acc[o+3],acc[o+3], s))));
  }
  s += __shfl_xor(s, 1);
  if (hf == 0) sq2[n] = s;
}

// ---------------- knn2 phase A: exact top-10 over j in [0,256) + threshold ----------------
__global__ __launch_bounds__(256,1) void knn2_thresh(const float* __restrict__ x1,
    const float* __restrict__ sq2,
    float* __restrict__ seed_d, int* __restrict__ seed_i, float* __restrict__ Tout){
  __shared__ alignas(16) float sj[64*64];    // 16 KB
  __shared__ float ssq[64];
  int b  = blockIdx.x >> 2;
  int ig = blockIdx.x & 3;
  int t = threadIdx.x;
  int n = b*NP + ig*256 + t;
  float xi[64];
  #pragma unroll
  for (int c=0;c<64;c+=4){
    float4 v = *(const float4*)&x1[(size_t)n*64+c];
    xi[c]=v.x; xi[c+1]=v.y; xi[c+2]=v.z; xi[c+3]=v.w;
  }
  float sqi = sq2[n];
  float bd[KNN]; int bi[KNN];
  #pragma unroll
  for (int s=0;s<KNN;++s){ bd[s]=FLT_MAX; bi[s]=0; }
  for (int tile=0; tile<4; ++tile){
    __syncthreads();
    const float4* src = (const float4*)(x1 + ((size_t)b*NP + tile*64)*64);
    for (int u=t; u<1024; u+=256) ((float4*)sj)[u] = src[u];
    if (t < 64) ssq[t] = sq2[b*NP + tile*64 + t];
    __syncthreads();
    #pragma unroll 1
    for (int j=0;j<64;++j){
      float dot = 0.0f;
      #pragma unroll
      for (int c=0;c<64;c+=4){
        float4 v = *(const float4*)&sj[j*64+c];
        dot = fmaf(xi[c+0],v.x,dot); dot = fmaf(xi[c+1],v.y,dot);
        dot = fmaf(xi[c+2],v.z,dot); dot = fmaf(xi[c+3],v.w,dot);
      }
      float d2 = (sqi + ssq[j]) - 2.0f*dot;
      if (d2 < bd[KNN-1]){
        TOP10_INSERT(d2, tile*64+j, bd, bi);
      }
    }
  }
  #pragma unroll
  for (int s=0;s<KNN;++s){
    seed_d[(size_t)n*KNN + s] = bd[s];
    seed_i[(size_t)n*KNN + s] = bi[s];
  }
  Tout[n] = bd[KNN-1];
}

// ---------------- knn2 phase B: filtered scan of j in [256,1024), 4 chunks ----------------
__global__ __launch_bounds__(256,2) void knn2_scan(const float* __restrict__ x1,
    const float* __restrict__ sq2, const float* __restrict__ Tin,
    float2* __restrict__ surv, int* __restrict__ cnt4){
  __shared__ alignas(16) float sj[96*64];    // 24 KB
  __shared__ float ssq[96];
  int bid = blockIdx.x;     // 1024 = 64 b x 4 ig x 4 jc
  int b  = bid >> 4;
  int ig = (bid >> 2) & 3;
  int jc = bid & 3;
  int t = threadIdx.x;
  int n = b*NP + ig*256 + t;
  float xi[64];
  #pragma unroll
  for (int c=0;c<64;c+=4){
    float4 v = *(const float4*)&x1[(size_t)n*64+c];
    xi[c]=v.x; xi[c+1]=v.y; xi[c+2]=v.z; xi[c+3]=v.w;
  }
  float sqi = sq2[n];
  float thr = Tin[n];
  int cnt = 0;
  float2* mybuf = surv + ((size_t)n*4 + jc)*SCAP;
  int jbase0 = 256 + jc*192;
  for (int tile=0; tile<2; ++tile){
    int jb = jbase0 + tile*96;
    __syncthreads();
    const float4* src = (const float4*)(x1 + ((size_t)b*NP + jb)*64);
    for (int u=t; u<1536; u+=256) ((float4*)sj)[u] = src[u];
    if (t < 96) ssq[t] = sq2[b*NP + jb + t];
    __syncthreads();
    #pragma unroll 1
    for (int j=0;j<96;++j){
      float dot = 0.0f;
      #pragma unroll
      for (int c=0;c<64;c+=4){
        float4 v = *(const float4*)&sj[j*64+c];
        dot = fmaf(xi[c+0],v.x,dot); dot = fmaf(xi[c+1],v.y,dot);
        dot = fmaf(xi[c+2],v.z,dot); dot = fmaf(xi[c+3],v.w,dot);
      }
      float d2 = (sqi + ssq[j]) - 2.0f*dot;
      if (d2 <= thr && cnt < SCAP){
        float2 e; e.x = d2; e.y = __int_as_float(jb + j);
        mybuf[cnt] = e;
        cnt++;
      }
    }
  }
  cnt4[(size_t)n*4 + jc] = cnt;
}

// ---------------- knn2 phase C: replay survivors into seed list ----------------
__global__ void knn2_select(const float* __restrict__ seed_d, const int* __restrict__ seed_i,
    const float2* __restrict__ surv, const int* __restrict__ cnt4,
    int* __restrict__ idx2){
  int n = blockIdx.x*256 + threadIdx.x;
  float bd[KNN]; int bi[KNN];
  #pragma unroll
  for (int s=0;s<KNN;++s){
    bd[s] = seed_d[(size_t)n*KNN + s];
    bi[s] = seed_i[(size_t)n*KNN + s];
  }
  #pragma unroll 1
  for (int c=0;c<4;++c){
    int nc = cnt4[(size_t)n*4 + c];
    const float2* buf = surv + ((size_t)n*4 + c)*SCAP;
    #pragma unroll 1
    for (int k=0;k<nc;++k){
      float2 e = buf[k];
      float d = e.x; int j = __float_as_int(e.y);
      if (d < bd[KNN-1]){
        TOP10_INSERT(d, j, bd, bi);
      }
    }
  }
  #pragma unroll
  for (int s=0;s<KNN;++s) idx2[(size_t)n*KNN+s] = bi[s];
}

// ---------------- q/r GEMM for edgeconv2: q=x1*Wbot, r=x1*(Wtop-Wbot)+b ----------------
__global__ __launch_bounds__(256,1) void qr2_kernel(const float* __restrict__ x1,
    const float* __restrict__ wcombg, const float* __restrict__ b2,
    float* __restrict__ q2, float* __restrict__ r2){
  __shared__ alignas(16) float sw[16384];    // 64 KB
  __shared__ float sb2[128];
  int t = threadIdx.x;
  for (int u=t; u<4096; u+=256) ((float4*)sw)[u] = ((const float4*)wcombg)[u];
  if (t < 128) sb2[t] = b2[t];
  __syncthreads();
  int n = blockIdx.x*256 + t;
  float xi[64];
  #pragma unroll
  for (int c=0;c<64;c+=4){
    float4 v = *(const float4*)&x1[(size_t)n*64+c];
    xi[c]=v.x; xi[c+1]=v.y; xi[c+2]=v.z; xi[c+3]=v.w;
  }
  #pragma unroll 1
  for (int op=0; op<128; op+=4){
    float q0=0,q1=0,q2a=0,q3=0, r0,r1,r2a,r3;
    r0=sb2[op]; r1=sb2[op+1]; r2a=sb2[op+2]; r3=sb2[op+3];
    #pragma unroll
    for (int c=0;c<64;c+=4){
      float4 a0 = *(const float4*)&sw[(op+0)*64+c];
      float4 a1 = *(const float4*)&sw[(op+1)*64+c];
      float4 a2 = *(const float4*)&sw[(op+2)*64+c];
      float4 a3 = *(const float4*)&sw[(op+3)*64+c];
      float4 c0 = *(const float4*)&sw[(128+op+0)*64+c];
      float4 c1 = *(const float4*)&sw[(128+op+1)*64+c];
      float4 c2 = *(const float4*)&sw[(128+op+2)*64+c];
      float4 c3 = *(const float4*)&sw[(128+op+3)*64+c];
      q0=fmaf(xi[c],a0.x,q0); q0=fmaf(xi[c+1],a0.y,q0); q0=fmaf(xi[c+2],a0.z,q0); q0=fmaf(xi[c+3],a0.w,q0);
      q1=fmaf(xi[c],a1.x,q1); q1=fmaf(xi[c+1],a1.y,q1); q1=fmaf(xi[c+2],a1.z,q1); q1=fmaf(xi[c+3],a1.w,q1);
      q2a=fmaf(xi[c],a2.x,q2a); q2a=fmaf(xi[c+1],a2.y,q2a); q2a=fmaf(xi[c+2],a2.z,q2a); q2a=fmaf(xi[c+3],a2.w,q2a);
      q3=fmaf(xi[c],a3.x,q3); q3=fmaf(xi[c+1],a3.y,q3); q3=fmaf(xi[c+2],a3.z,q3); q3=fmaf(xi[c+3],a3.w,q3);
      r0=fmaf(xi[c],c0.x,r0); r0=fmaf(xi[c+1],c0.y,r0); r0=fmaf(xi[c+2],c0.z,r0); r0=fmaf(xi[c+3],c0.w,r0);
      r1=fmaf(xi[c],c1.x,r1); r1=fmaf(xi[c+1],c1.y,r1); r1=fmaf(xi[c+2],c1.z,r1); r1=fmaf(xi[c+3],c1.w,r1);
      r2a=fmaf(xi[c],c2.x,r2a); r2a=fmaf(xi[c+1],c2.y,r2a); r2a=fmaf(xi[c+2],c2.z,r2a); r2a=fmaf(xi[c+3],c2.w,r2a);
      r3=fmaf(xi[c],c3.x,r3); r3=fmaf(xi[c+1],c3.y,r3); r3=fmaf(xi[c+2],c3.z,r3); r3=fmaf(xi[c+3],c3.w,r3);
    }
    float4 qv; qv.x=q0; qv.y=q1; qv.z=q2a; qv.w=q3;
    float4 rv; rv.x=r0; rv.y=r1; rv.z=r2a; rv.w=r3;
    *(float4*)&q2[(size_t)n*128+op] = qv;
    *(float4*)&r2[(size_t)n*128+op] = rv;
  }
}

// ---------------- edgeconv2 gather + fused mean (never materialize x2) ----------------
__global__ __launch_bounds__(256,4) void ec2_gather_kernel(
    const float* __restrict__ q2, const float* __restrict__ r2,
    const int* __restrict__ idx2, float* __restrict__ fmean){
  __shared__ alignas(16) float4 red[256];
  int t = threadIdx.x;
  int b = blockIdx.x >> 7, blk = blockIdx.x & 127;
  int p = t >> 5, c4 = t & 31;
  int n = b*NP + blk*8 + p;
  float4 r = *(const float4*)&r2[(size_t)n*128 + c4*4];
  float4 acc; acc.x=0; acc.y=0; acc.z=0; acc.w=0;
  #pragma unroll 1
  for (int k=0;k<KNN;++k){
    int j = idx2[n*KNN+k];
    float4 qv = *(const float4*)&q2[((size_t)b*NP + j)*128 + c4*4];
    acc.x += lrelu(r.x+qv.x);
    acc.y += lrelu(r.y+qv.y);
    acc.z += lrelu(r.z+qv.z);
    acc.w += lrelu(r.w+qv.w);
  }
  red[t] = acc;
  __syncthreads();
  if (t < 128){ float4 o = red[t+128]; red[t].x+=o.x; red[t].y+=o.y; red[t].z+=o.z; red[t].w+=o.w; }
  __syncthreads();
  if (t < 64){ float4 o = red[t+64]; red[t].x+=o.x; red[t].y+=o.y; red[t].z+=o.z; red[t].w+=o.w; }
  __syncthreads();
  if (t < 32){
    float4 s = red[t]; float4 o = red[t+32];
    s.x+=o.x; s.y+=o.y; s.z+=o.z; s.w+=o.w;
    float* dst = &fmean[b*192 + 64 + c4*4];
    atomicAdd(dst+0, s.x); atomicAdd(dst+1, s.y);
    atomicAdd(dst+2, s.z); atomicAdd(dst+3, s.w);
  }
}

// ---------------- mean of x1 -> fmean[:,0:64] (sums; /1024 applied in head) ----------------
__global__ __launch_bounds__(256,4) void mean1_kernel(const float* __restrict__ x1,
                                                      float* __restrict__ fmean){
  __shared__ float red[256];
  int t = threadIdx.x;
  int b = blockIdx.x >> 2, qq = blockIdx.x & 3;
  int c = t & 63, pl = t >> 6;
  float s = 0.0f;
  for (int i=0;i<64;++i){
    int p = qq*256 + pl + 4*i;
    s += x1[((size_t)b*NP + p)*64 + c];
  }
  red[t] = s;
  __syncthreads();
  if (t < 128) red[t] += red[t+128];
  __syncthreads();
  if (t < 64) atomicAdd(&fmean[b*192 + c], red[t] + red[t+64]);
}

// ---------------- head, split for parallelism ----------------
__global__ __launch_bounds__(256) void headA_kernel(const float* __restrict__ fmean,
    const float* __restrict__ wl, const float* __restrict__ bl,
    float* __restrict__ o1g){
  __shared__ float v0[192];
  int b = blockIdx.x >> 2, ch = blockIdx.x & 3, t = threadIdx.x;
  if (t < 192) v0[t] = fmean[b*192 + t] * (1.0f/1024.0f);
  __syncthreads();
  int o = ch*256 + t;
  float s = bl[o];
  #pragma unroll 8
  for (int c=0;c<192;++c) s = fmaf(v0[c], wl[c*1024 + o], s);
  o1g[b*1024 + o] = s;
}

__global__ __launch_bounds__(256) void headB_kernel(const float* __restrict__ o1g,
    const float* __restrict__ wm1, const float* __restrict__ bm1,
    float* __restrict__ h1g){
  __shared__ alignas(16) float vo[1024];
  int b = blockIdx.x >> 1, ch = blockIdx.x & 1, t = threadIdx.x;
  ((float4*)vo)[t] = ((const float4*)(o1g + b*1024))[t];
  __syncthreads();
  int o = ch*256 + t;
  float s = bm1[o];
  #pragma unroll 8
  for (int c=0;c<1024;++c) s = fmaf(vo[c], wm1[c*512 + o], s);
  h1g[b*512 + o] = lrelu(s);
}

__global__ __launch_bounds__(256) void headC_kernel(const float* __restrict__ h1g,
    const float* __restrict__ wm2, const float* __restrict__ bm2,
    const float* __restrict__ wm3, const float* __restrict__ bm3,
    float* __restrict__ out){
  __shared__ alignas(16) float vh[512];
  __shared__ float h2[256];
  int b = blockIdx.x, t = threadIdx.x;
  ((float2*)vh)[t] = ((const float2*)(h1g + b*512))[t];
  __syncthreads();
  float s = bm2[t];
  #pragma unroll 8
  for (int c=0;c<512;++c) s = fmaf(vh[c], wm2[c*256 + t], s);
  h2[t] = lrelu(s);
  __syncthreads();
  if (t < 3){
    float s2 = bm3[t];
    #pragma unroll 8
    for (int c=0;c<256;++c) s2 = fmaf(h2[c], wm3[c*3 + t], s2);
    out[b*3 + t] = s2;
  }
}

extern "C" void kernel_launch(void* const* d_in, const int* in_sizes, int n_in,
                              void* d_out, int out_size, void* d_ws, size_t ws_size,
                              hipStream_t stream) {
  const float* x   = (const float*)d_in[0];
  const float* pos = (const float*)d_in[1];
  const float* w1a = (const float*)d_in[3];
  const float* b1a = (const float*)d_in[4];
  const float* w1b = (const float*)d_in[5];
  const float* b1b = (const float*)d_in[6];
  const float* w1c = (const float*)d_in[7];
  const float* b1c = (const float*)d_in[8];
  const float* w2  = (const float*)d_in[9];
  const float* b2  = (const float*)d_in[10];
  const float* wl  = (const float*)d_in[11];
  const float* bl  = (const float*)d_in[12];
  const float* wm1 = (const float*)d_in[13];
  const float* bm1 = (const float*)d_in[14];
  const float* wm2 = (const float*)d_in[15];
  const float* bm2 = (const float*)d_in[16];
  const float* wm3 = (const float*)d_in[17];
  const float* bm3 = (const float*)d_in[18];
  float* out = (float*)d_out;

  float* ws_f  = (float*)d_ws;
  float* xx    = ws_f;                    // 262144 f
  float* x1    = xx + 262144;             // 4194304 f (16 MB)
  float* sq2   = x1 + 4194304;            // 65536 f
  int*   idx1  = (int*)(sq2 + 65536);     // 655360 i
  int*   idx2  = idx1 + 655360;           // 655360 i
  float* q2    = (float*)(idx2 + 655360); // 8388608 f (32 MB)
  float* r2    = q2 + 8388608;            // 8388608 f (32 MB)
  float* wcomb = r2 + 8388608;            // 16384 f
  float* fmean = wcomb + 16384;           // 12288 f
  float* o1g   = fmean + 12288;           // 65536 f
  float* h1g   = o1g + 65536;             // 32768 f
  float* seedd = h1g + 32768;             // 655360 f
  int*   seedi = (int*)(seedd + 655360);  // 655360 i
  float* Tbuf  = (float*)(seedi + 655360);// 65536 f
  int*   cnt4  = (int*)(Tbuf + 65536);    // 262144 i
  // Temporal overlays (consumed before qr2 writes q2/r2):
  float* bdh1  = r2;                      // knn1: 2621440 f
  int*   bih1  = (int*)(r2 + 2621440);    // knn1: 2621440 i
  float2* surv = (float2*)q2;             // knn2 survivors: 65536*4*30*8B

  prep_fused<<<368, 256, 0, stream>>>(x, pos, w2, xx, wcomb, fmean);
  knn1_kernel<<<1024, 256, 0, stream>>>(xx, bdh1, bih1);
  merge4_kernel<<<256, 256, 0, stream>>>(bdh1, bih1, idx1);
  edgeconv1_kernel<<<512, 256, 0, stream>>>(xx, idx1, w1a, b1a, w1b, b1b, w1c, b1c, x1, sq2);
  knn2_thresh<<<256, 256, 0, stream>>>(x1, sq2, seedd, seedi, Tbuf);
  knn2_scan<<<1024, 256, 0, stream>>>(x1, sq2, Tbuf, surv, cnt4);
  knn2_select<<<256, 256, 0, stream>>>(seedd, seedi, surv, cnt4, idx2);
  qr2_kernel<<<256, 256, 0, stream>>>(x1, wcomb, b2, q2, r2);
  ec2_gather_kernel<<<8192, 256, 0, stream>>>(q2, r2, idx2, fmean);
  mean1_kernel<<<256, 256, 0, stream>>>(x1, fmean);
  headA_kernel<<<256, 256, 0, stream>>>(fmean, wl, bl, o1g);
  headB_kernel<<<128, 256, 0, stream>>>(o1g, wm1, bm1, h1g);
  headC_kernel<<<64, 256, 0, stream>>>(h1g, wm2, bm2, wm3, bm3, out);
}

// Round 14
// 957.268 us; speedup vs baseline: 8.6441x; 1.0877x over previous
//
#include <hip/hip_runtime.h>
#include <float.h>

#define NB 64
#define NP 1024
#define KNN 10
#define SCAP 30   // survivors per (point, j-chunk)

__device__ __forceinline__ float lrelu(float v){ return v >= 0.0f ? v : 0.01f*v; }

// sorted-ascending bubble insert; strict < keeps earlier-inserted (lower j) on ties.
// Only static data flow (no runtime-indexed register arrays — R6 spill lesson).
#define TOP10_INSERT(dk_, ik_, bd_, bi_)              \
  { float dk=dk_; int ik=ik_;                         \
    _Pragma("unroll")                                 \
    for (int s=0;s<KNN;++s){                          \
      bool sw = dk < bd_[s];                          \
      float td=bd_[s]; int ti=bi_[s];                 \
      bd_[s]=sw?dk:td; bi_[s]=sw?ik:ti;               \
      dk=sw?td:dk;     ik=sw?ti:ik; } }

// ---------------- fused prep: build xx, wcomb, zero fmean ----------------
__global__ void prep_fused(const float* __restrict__ x, const float* __restrict__ pos,
                           const float* __restrict__ w2,
                           float* __restrict__ xx, float* __restrict__ wcomb,
                           float* __restrict__ fmean){
  int tid = blockIdx.x*256 + threadIdx.x;   // grid 368 -> 94208 threads
  if (tid < 65536){
    float4 v;
    v.x = x[tid];
    v.y = pos[3*tid+0];
    v.z = pos[3*tid+1];
    v.w = pos[3*tid+2];
    ((float4*)xx)[tid] = v;
  } else if (tid < 65536+16384){
    int i = tid - 65536;
    int op = i >> 6, c = i & 63;
    if (op < 128){
      wcomb[i] = w2[(64+c)*128 + op];
    } else {
      int o = op - 128;
      wcomb[i] = w2[c*128 + o] - w2[(64+c)*128 + o];
    }
  } else {
    int i = tid - 65536 - 16384;
    if (i < NB*192) fmean[i] = 0.0f;
  }
}

// ---------------- knn1: 4-dim features, 4 i-quarters x 4 j-quarters ----------------
__global__ __launch_bounds__(256,2) void knn1_kernel(const float* __restrict__ xx,
                                                     float* __restrict__ bdh1,
                                                     int* __restrict__ bih1){
  __shared__ alignas(16) float sf[256*4];   // 4 KB j-quarter points
  __shared__ float ssq[256];
  int bid = blockIdx.x;        // 1024 = 64 b x 4 iq x 4 jq
  int b  = bid >> 4;
  int iq = (bid >> 2) & 3;
  int jq = bid & 3;
  int t = threadIdx.x;
  {
    float4 v = ((const float4*)xx)[(size_t)b*NP + jq*256 + t];
    ((float4*)sf)[t] = v;
    ssq[t] = ((v.x*v.x + v.y*v.y) + v.z*v.z) + v.w*v.w;
  }
  __syncthreads();
  int il = iq*256 + t;
  int n = b*NP + il;
  float4 fi = ((const float4*)xx)[n];
  float sqi = ((fi.x*fi.x + fi.y*fi.y) + fi.z*fi.z) + fi.w*fi.w;
  float bd[KNN]; int bi[KNN];
  #pragma unroll
  for (int s=0;s<KNN;++s){ bd[s]=FLT_MAX; bi[s]=0; }
  #pragma unroll 1
  for (int j=0;j<256;++j){
    float4 fj = ((float4*)sf)[j];
    float dot = fi.x*fj.x + fi.y*fj.y + fi.z*fj.z + fi.w*fj.w;
    float d2 = (sqi + ssq[j]) - 2.0f*dot;
    if (d2 < bd[KNN-1]){
      TOP10_INSERT(d2, jq*256+j, bd, bi);
    }
  }
  #pragma unroll
  for (int s=0;s<KNN;++s){
    bdh1[((size_t)n*4 + jq)*KNN + s] = bd[s];
    bih1[((size_t)n*4 + jq)*KNN + s] = bi[s];
  }
}

// ---------------- fold-merge of 4 sorted lists (ties -> lower list = lower j) ----------------
__global__ void merge4_kernel(const float* __restrict__ bdh, const int* __restrict__ bih,
                              int* __restrict__ idx){
  int n = blockIdx.x*256 + threadIdx.x;
  float A[KNN]; int Ai[KNN];
  #pragma unroll
  for (int s=0;s<KNN;++s){
    A[s]  = bdh[(size_t)n*4*KNN + s];
    Ai[s] = bih[(size_t)n*4*KNN + s];
  }
  #pragma unroll
  for (int q=1;q<4;++q){
    float T[KNN]; int Ti[KNN];
    #pragma unroll
    for (int s=0;s<KNN;++s){
      T[s]  = bdh[((size_t)n*4+q)*KNN + s];
      Ti[s] = bih[((size_t)n*4+q)*KNN + s];
    }
    float O[KNN]; int Oi[KNN];
    #pragma unroll
    for (int s=0;s<KNN;++s){
      bool ta = A[0] <= T[0];
      O[s]  = ta ? A[0]  : T[0];
      Oi[s] = ta ? Ai[0] : Ti[0];
      #pragma unroll
      for (int u=0;u<KNN-1;++u){
        A[u]  = ta ? A[u+1]  : A[u];
        Ai[u] = ta ? Ai[u+1] : Ai[u];
        T[u]  = ta ? T[u]    : T[u+1];
        Ti[u] = ta ? Ti[u]   : Ti[u+1];
      }
    }
    #pragma unroll
    for (int s=0;s<KNN;++s){ A[s]=O[s]; Ai[s]=Oi[s]; }
  }
  #pragma unroll
  for (int s=0;s<KNN;++s) idx[(size_t)n*KNN+s] = Ai[s];
}

// ---------------- edgeconv1: 4 threads/point, 16 outputs, 2-edge batch, h in LDS ----------------
// Weight ds_read amortized over 2 edges (4 b128 + 2 b32 per c vs R10's 8+1 per
// edge). h rows live in LDS (NOT registers, NOT shfl sources — R11/R12 spill
// lessons). Live set pr0[16]+pr1[16]+acc[16]=48 floats. LDS 67.3 KB -> 2
// blocks/CU (same as R10).
__global__ __launch_bounds__(256,2) void edgeconv1_kernel(
    const float* __restrict__ xx, const int* __restrict__ idx1,
    const float* __restrict__ w1a, const float* __restrict__ b1a,
    const float* __restrict__ w1b, const float* __restrict__ b1b,
    const float* __restrict__ w1c, const float* __restrict__ b1c,
    float* __restrict__ x1, float* __restrict__ sq2){
  __shared__ alignas(16) float swa[512];     //  2 KB w1a [c][o]
  __shared__ alignas(16) float swb[4096];    // 16 KB w1b [c][o]
  __shared__ alignas(16) float swc[4096];    // 16 KB w1c [c][o]
  __shared__ float sba[64], sbb[64], sbc[64];
  __shared__ float hx0[64*65];               // 16.6 KB edge-0 h rows
  __shared__ float hx1[64*65];               // 16.6 KB edge-1 h rows
  int t = threadIdx.x;
  for (int i=t; i<128;  i+=256) ((float4*)swa)[i] = ((const float4*)w1a)[i];
  for (int i=t; i<1024; i+=256) ((float4*)swb)[i] = ((const float4*)w1b)[i];
  for (int i=t; i<1024; i+=256) ((float4*)swc)[i] = ((const float4*)w1c)[i];
  if (t < 64){ sba[t]=b1a[t]; sbb[t]=b1b[t]; sbc[t]=b1c[t]; }
  __syncthreads();

  int p  = t >> 2;           // local point 0..63
  int q  = t & 3;            // channel quarter
  int cb = q*16;
  int b  = blockIdx.x >> 4;  // batch
  int g  = blockIdx.x & 15;  // point group
  int n  = b*NP + g*64 + p;
  float* h0row = &hx0[p*65];
  float* h1row = &hx1[p*65];

  float4 fi = ((const float4*)xx)[n];
  float acc[16];
  #pragma unroll
  for (int o=0;o<16;++o) acc[o]=0.0f;

  #pragma unroll 1
  for (int kp=0; kp<5; ++kp){
    int j0 = idx1[n*KNN + kp*2];
    int j1 = idx1[n*KNN + kp*2 + 1];
    float4 fj0 = ((const float4*)xx)[b*NP + j0];
    float4 fj1 = ((const float4*)xx)[b*NP + j1];
    float e0[8], e1[8];
    e0[0]=fi.x; e0[1]=fi.y; e0[2]=fi.z; e0[3]=fi.w;
    e0[4]=fj0.x-fi.x; e0[5]=fj0.y-fi.y; e0[6]=fj0.z-fi.z; e0[7]=fj0.w-fi.w;
    e1[0]=fi.x; e1[1]=fi.y; e1[2]=fi.z; e1[3]=fi.w;
    e1[4]=fj1.x-fi.x; e1[5]=fj1.y-fi.y; e1[6]=fj1.z-fi.z; e1[7]=fj1.w-fi.w;

    // ---- layer a: 8 -> my 16 channels, both edges share weight reads
    {
      float pr0[16], pr1[16];
      #pragma unroll
      for (int o=0;o<16;++o){ float bb=sba[cb+o]; pr0[o]=bb; pr1[o]=bb; }
      #pragma unroll
      for (int c=0;c<8;++c){
        #pragma unroll
        for (int o4=0;o4<4;++o4){
          float4 w = *(const float4*)&swa[c*64 + cb + o4*4];
          pr0[o4*4+0]=fmaf(e0[c],w.x,pr0[o4*4+0]);
          pr0[o4*4+1]=fmaf(e0[c],w.y,pr0[o4*4+1]);
          pr0[o4*4+2]=fmaf(e0[c],w.z,pr0[o4*4+2]);
          pr0[o4*4+3]=fmaf(e0[c],w.w,pr0[o4*4+3]);
          pr1[o4*4+0]=fmaf(e1[c],w.x,pr1[o4*4+0]);
          pr1[o4*4+1]=fmaf(e1[c],w.y,pr1[o4*4+1]);
          pr1[o4*4+2]=fmaf(e1[c],w.z,pr1[o4*4+2]);
          pr1[o4*4+3]=fmaf(e1[c],w.w,pr1[o4*4+3]);
        }
      }
      #pragma unroll
      for (int o=0;o<16;++o){ h0row[cb+o]=lrelu(pr0[o]); h1row[cb+o]=lrelu(pr1[o]); }
    }
    __syncthreads();

    // ---- layer b: full h rows from LDS, my 16 outputs, both edges
    float pr0[16], pr1[16];
    #pragma unroll
    for (int o=0;o<16;++o){ float bb=sbb[cb+o]; pr0[o]=bb; pr1[o]=bb; }
    #pragma unroll 4
    for (int c=0;c<64;++c){
      float hv0 = h0row[c];
      float hv1 = h1row[c];
      #pragma unroll
      for (int o4=0;o4<4;++o4){
        float4 w = *(const float4*)&swb[c*64 + cb + o4*4];
        pr0[o4*4+0]=fmaf(hv0,w.x,pr0[o4*4+0]);
        pr0[o4*4+1]=fmaf(hv0,w.y,pr0[o4*4+1]);
        pr0[o4*4+2]=fmaf(hv0,w.z,pr0[o4*4+2]);
        pr0[o4*4+3]=fmaf(hv0,w.w,pr0[o4*4+3]);
        pr1[o4*4+0]=fmaf(hv1,w.x,pr1[o4*4+0]);
        pr1[o4*4+1]=fmaf(hv1,w.y,pr1[o4*4+1]);
        pr1[o4*4+2]=fmaf(hv1,w.z,pr1[o4*4+2]);
        pr1[o4*4+3]=fmaf(hv1,w.w,pr1[o4*4+3]);
      }
    }
    __syncthreads();              // all h1 reads done before overwrite
    #pragma unroll
    for (int o=0;o<16;++o){ h0row[cb+o]=lrelu(pr0[o]); h1row[cb+o]=lrelu(pr1[o]); }
    __syncthreads();

    // ---- layer c: accumulate my 16 outputs, both edges
    #pragma unroll
    for (int o=0;o<16;++o){ float bb=sbc[cb+o]; pr0[o]=bb; pr1[o]=bb; }
    #pragma unroll 4
    for (int c=0;c<64;++c){
      float hv0 = h0row[c];
      float hv1 = h1row[c];
      #pragma unroll
      for (int o4=0;o4<4;++o4){
        float4 w = *(const float4*)&swc[c*64 + cb + o4*4];
        pr0[o4*4+0]=fmaf(hv0,w.x,pr0[o4*4+0]);
        pr0[o4*4+1]=fmaf(hv0,w.y,pr0[o4*4+1]);
        pr0[o4*4+2]=fmaf(hv0,w.z,pr0[o4*4+2]);
        pr0[o4*4+3]=fmaf(hv0,w.w,pr0[o4*4+3]);
        pr1[o4*4+0]=fmaf(hv1,w.x,pr1[o4*4+0]);
        pr1[o4*4+1]=fmaf(hv1,w.y,pr1[o4*4+1]);
        pr1[o4*4+2]=fmaf(hv1,w.z,pr1[o4*4+2]);
        pr1[o4*4+3]=fmaf(hv1,w.w,pr1[o4*4+3]);
      }
    }
    #pragma unroll
    for (int o=0;o<16;++o) acc[o] += lrelu(pr0[o]) + lrelu(pr1[o]);
    __syncthreads();              // rows free for next pair
  }

  float s = 0.0f;
  #pragma unroll
  for (int o=0;o<16;o+=4){
    float4 v; v.x=acc[o]; v.y=acc[o+1]; v.z=acc[o+2]; v.w=acc[o+3];
    *(float4*)&x1[(size_t)n*64 + cb + o] = v;
    s = fmaf(acc[o],acc[o], fmaf(acc[o+1],acc[o+1], fmaf(acc[o+2],acc[o+2], fmaf(acc[o+3],acc[o+3], s))));
  }
  s += __shfl_xor(s, 1);
  s += __shfl_xor(s, 2);
  if (q == 0) sq2[n] = s;
}

// ---------------- knn2 phase A: exact top-10 over j in [0,256) + threshold ----------------
__global__ __launch_bounds__(256,1) void knn2_thresh(const float* __restrict__ x1,
    const float* __restrict__ sq2,
    float* __restrict__ seed_d, int* __restrict__ seed_i, float* __restrict__ Tout){
  __shared__ alignas(16) float sj[64*64];    // 16 KB
  __shared__ float ssq[64];
  int b  = blockIdx.x >> 2;
  int ig = blockIdx.x & 3;
  int t = threadIdx.x;
  int n = b*NP + ig*256 + t;
  float xi[64];
  #pragma unroll
  for (int c=0;c<64;c+=4){
    float4 v = *(const float4*)&x1[(size_t)n*64+c];
    xi[c]=v.x; xi[c+1]=v.y; xi[c+2]=v.z; xi[c+3]=v.w;
  }
  float sqi = sq2[n];
  float bd[KNN]; int bi[KNN];
  #pragma unroll
  for (int s=0;s<KNN;++s){ bd[s]=FLT_MAX; bi[s]=0; }
  for (int tile=0; tile<4; ++tile){
    __syncthreads();
    const float4* src = (const float4*)(x1 + ((size_t)b*NP + tile*64)*64);
    for (int u=t; u<1024; u+=256) ((float4*)sj)[u] = src[u];
    if (t < 64) ssq[t] = sq2[b*NP + tile*64 + t];
    __syncthreads();
    #pragma unroll 1
    for (int j=0;j<64;++j){
      float dot = 0.0f;
      #pragma unroll
      for (int c=0;c<64;c+=4){
        float4 v = *(const float4*)&sj[j*64+c];
        dot = fmaf(xi[c+0],v.x,dot); dot = fmaf(xi[c+1],v.y,dot);
        dot = fmaf(xi[c+2],v.z,dot); dot = fmaf(xi[c+3],v.w,dot);
      }
      float d2 = (sqi + ssq[j]) - 2.0f*dot;
      if (d2 < bd[KNN-1]){
        TOP10_INSERT(d2, tile*64+j, bd, bi);
      }
    }
  }
  #pragma unroll
  for (int s=0;s<KNN;++s){
    seed_d[(size_t)n*KNN + s] = bd[s];
    seed_i[(size_t)n*KNN + s] = bi[s];
  }
  Tout[n] = bd[KNN-1];
}

// ---------------- knn2 phase B: filtered scan of j in [256,1024), 4 chunks ----------------
__global__ __launch_bounds__(256,2) void knn2_scan(const float* __restrict__ x1,
    const float* __restrict__ sq2, const float* __restrict__ Tin,
    float2* __restrict__ surv, int* __restrict__ cnt4){
  __shared__ alignas(16) float sj[96*64];    // 24 KB
  __shared__ float ssq[96];
  int bid = blockIdx.x;     // 1024 = 64 b x 4 ig x 4 jc
  int b  = bid >> 4;
  int ig = (bid >> 2) & 3;
  int jc = bid & 3;
  int t = threadIdx.x;
  int n = b*NP + ig*256 + t;
  float xi[64];
  #pragma unroll
  for (int c=0;c<64;c+=4){
    float4 v = *(const float4*)&x1[(size_t)n*64+c];
    xi[c]=v.x; xi[c+1]=v.y; xi[c+2]=v.z; xi[c+3]=v.w;
  }
  float sqi = sq2[n];
  float thr = Tin[n];
  int cnt = 0;
  float2* mybuf = surv + ((size_t)n*4 + jc)*SCAP;
  int jbase0 = 256 + jc*192;
  for (int tile=0; tile<2; ++tile){
    int jb = jbase0 + tile*96;
    __syncthreads();
    const float4* src = (const float4*)(x1 + ((size_t)b*NP + jb)*64);
    for (int u=t; u<1536; u+=256) ((float4*)sj)[u] = src[u];
    if (t < 96) ssq[t] = sq2[b*NP + jb + t];
    __syncthreads();
    #pragma unroll 1
    for (int j=0;j<96;++j){
      float dot = 0.0f;
      #pragma unroll
      for (int c=0;c<64;c+=4){
        float4 v = *(const float4*)&sj[j*64+c];
        dot = fmaf(xi[c+0],v.x,dot); dot = fmaf(xi[c+1],v.y,dot);
        dot = fmaf(xi[c+2],v.z,dot); dot = fmaf(xi[c+3],v.w,dot);
      }
      float d2 = (sqi + ssq[j]) - 2.0f*dot;
      if (d2 <= thr && cnt < SCAP){
        float2 e; e.x = d2; e.y = __int_as_float(jb + j);
        mybuf[cnt] = e;
        cnt++;
      }
    }
  }
  cnt4[(size_t)n*4 + jc] = cnt;
}

// ---------------- knn2 phase C: replay survivors into seed list ----------------
__global__ void knn2_select(const float* __restrict__ seed_d, const int* __restrict__ seed_i,
    const float2* __restrict__ surv, const int* __restrict__ cnt4,
    int* __restrict__ idx2){
  int n = blockIdx.x*256 + threadIdx.x;
  float bd[KNN]; int bi[KNN];
  #pragma unroll
  for (int s=0;s<KNN;++s){
    bd[s] = seed_d[(size_t)n*KNN + s];
    bi[s] = seed_i[(size_t)n*KNN + s];
  }
  #pragma unroll 1
  for (int c=0;c<4;++c){
    int nc = cnt4[(size_t)n*4 + c];
    const float2* buf = surv + ((size_t)n*4 + c)*SCAP;
    #pragma unroll 1
    for (int k=0;k<nc;++k){
      float2 e = buf[k];
      float d = e.x; int j = __float_as_int(e.y);
      if (d < bd[KNN-1]){
        TOP10_INSERT(d, j, bd, bi);
      }
    }
  }
  #pragma unroll
  for (int s=0;s<KNN;++s) idx2[(size_t)n*KNN+s] = bi[s];
}

// ---------------- q/r GEMM for edgeconv2: q=x1*Wbot, r=x1*(Wtop-Wbot)+b ----------------
__global__ __launch_bounds__(256,1) void qr2_kernel(const float* __restrict__ x1,
    const float* __restrict__ wcombg, const float* __restrict__ b2,
    float* __restrict__ q2, float* __restrict__ r2){
  __shared__ alignas(16) float sw[16384];    // 64 KB
  __shared__ float sb2[128];
  int t = threadIdx.x;
  for (int u=t; u<4096; u+=256) ((float4*)sw)[u] = ((const float4*)wcombg)[u];
  if (t < 128) sb2[t] = b2[t];
  __syncthreads();
  int n = blockIdx.x*256 + t;
  float xi[64];
  #pragma unroll
  for (int c=0;c<64;c+=4){
    float4 v = *(const float4*)&x1[(size_t)n*64+c];
    xi[c]=v.x; xi[c+1]=v.y; xi[c+2]=v.z; xi[c+3]=v.w;
  }
  #pragma unroll 1
  for (int op=0; op<128; op+=4){
    float q0=0,q1=0,q2a=0,q3=0, r0,r1,r2a,r3;
    r0=sb2[op]; r1=sb2[op+1]; r2a=sb2[op+2]; r3=sb2[op+3];
    #pragma unroll
    for (int c=0;c<64;c+=4){
      float4 a0 = *(const float4*)&sw[(op+0)*64+c];
      float4 a1 = *(const float4*)&sw[(op+1)*64+c];
      float4 a2 = *(const float4*)&sw[(op+2)*64+c];
      float4 a3 = *(const float4*)&sw[(op+3)*64+c];
      float4 c0 = *(const float4*)&sw[(128+op+0)*64+c];
      float4 c1 = *(const float4*)&sw[(128+op+1)*64+c];
      float4 c2 = *(const float4*)&sw[(128+op+2)*64+c];
      float4 c3 = *(const float4*)&sw[(128+op+3)*64+c];
      q0=fmaf(xi[c],a0.x,q0); q0=fmaf(xi[c+1],a0.y,q0); q0=fmaf(xi[c+2],a0.z,q0); q0=fmaf(xi[c+3],a0.w,q0);
      q1=fmaf(xi[c],a1.x,q1); q1=fmaf(xi[c+1],a1.y,q1); q1=fmaf(xi[c+2],a1.z,q1); q1=fmaf(xi[c+3],a1.w,q1);
      q2a=fmaf(xi[c],a2.x,q2a); q2a=fmaf(xi[c+1],a2.y,q2a); q2a=fmaf(xi[c+2],a2.z,q2a); q2a=fmaf(xi[c+3],a2.w,q2a);
      q3=fmaf(xi[c],a3.x,q3); q3=fmaf(xi[c+1],a3.y,q3); q3=fmaf(xi[c+2],a3.z,q3); q3=fmaf(xi[c+3],a3.w,q3);
      r0=fmaf(xi[c],c0.x,r0); r0=fmaf(xi[c+1],c0.y,r0); r0=fmaf(xi[c+2],c0.z,r0); r0=fmaf(xi[c+3],c0.w,r0);
      r1=fmaf(xi[c],c1.x,r1); r1=fmaf(xi[c+1],c1.y,r1); r1=fmaf(xi[c+2],c1.z,r1); r1=fmaf(xi[c+3],c1.w,r1);
      r2a=fmaf(xi[c],c2.x,r2a); r2a=fmaf(xi[c+1],c2.y,r2a); r2a=fmaf(xi[c+2],c2.z,r2a); r2a=fmaf(xi[c+3],c2.w,r2a);
      r3=fmaf(xi[c],c3.x,r3); r3=fmaf(xi[c+1],c3.y,r3); r3=fmaf(xi[c+2],c3.z,r3); r3=fmaf(xi[c+3],c3.w,r3);
    }
    float4 qv; qv.x=q0; qv.y=q1; qv.z=q2a; qv.w=q3;
    float4 rv; rv.x=r0; rv.y=r1; rv.z=r2a; rv.w=r3;
    *(float4*)&q2[(size_t)n*128+op] = qv;
    *(float4*)&r2[(size_t)n*128+op] = rv;
  }
}

// ---------------- edgeconv2 gather + fused mean (never materialize x2) ----------------
__global__ __launch_bounds__(256,4) void ec2_gather_kernel(
    const float* __restrict__ q2, const float* __restrict__ r2,
    const int* __restrict__ idx2, float* __restrict__ fmean){
  __shared__ alignas(16) float4 red[256];
  int t = threadIdx.x;
  int b = blockIdx.x >> 7, blk = blockIdx.x & 127;
  int p = t >> 5, c4 = t & 31;
  int n = b*NP + blk*8 + p;
  float4 r = *(const float4*)&r2[(size_t)n*128 + c4*4];
  float4 acc; acc.x=0; acc.y=0; acc.z=0; acc.w=0;
  #pragma unroll 1
  for (int k=0;k<KNN;++k){
    int j = idx2[n*KNN+k];
    float4 qv = *(const float4*)&q2[((size_t)b*NP + j)*128 + c4*4];
    acc.x += lrelu(r.x+qv.x);
    acc.y += lrelu(r.y+qv.y);
    acc.z += lrelu(r.z+qv.z);
    acc.w += lrelu(r.w+qv.w);
  }
  red[t] = acc;
  __syncthreads();
  if (t < 128){ float4 o = red[t+128]; red[t].x+=o.x; red[t].y+=o.y; red[t].z+=o.z; red[t].w+=o.w; }
  __syncthreads();
  if (t < 64){ float4 o = red[t+64]; red[t].x+=o.x; red[t].y+=o.y; red[t].z+=o.z; red[t].w+=o.w; }
  __syncthreads();
  if (t < 32){
    float4 s = red[t]; float4 o = red[t+32];
    s.x+=o.x; s.y+=o.y; s.z+=o.z; s.w+=o.w;
    float* dst = &fmean[b*192 + 64 + c4*4];
    atomicAdd(dst+0, s.x); atomicAdd(dst+1, s.y);
    atomicAdd(dst+2, s.z); atomicAdd(dst+3, s.w);
  }
}

// ---------------- mean of x1 -> fmean[:,0:64] (sums; /1024 applied in head) ----------------
__global__ __launch_bounds__(256,4) void mean1_kernel(const float* __restrict__ x1,
                                                      float* __restrict__ fmean){
  __shared__ float red[256];
  int t = threadIdx.x;
  int b = blockIdx.x >> 2, qq = blockIdx.x & 3;
  int c = t & 63, pl = t >> 6;
  float s = 0.0f;
  for (int i=0;i<64;++i){
    int p = qq*256 + pl + 4*i;
    s += x1[((size_t)b*NP + p)*64 + c];
  }
  red[t] = s;
  __syncthreads();
  if (t < 128) red[t] += red[t+128];
  __syncthreads();
  if (t < 64) atomicAdd(&fmean[b*192 + c], red[t] + red[t+64]);
}

// ---------------- head, split for parallelism ----------------
__global__ __launch_bounds__(256) void headA_kernel(const float* __restrict__ fmean,
    const float* __restrict__ wl, const float* __restrict__ bl,
    float* __restrict__ o1g){
  __shared__ float v0[192];
  int b = blockIdx.x >> 2, ch = blockIdx.x & 3, t = threadIdx.x;
  if (t < 192) v0[t] = fmean[b*192 + t] * (1.0f/1024.0f);
  __syncthreads();
  int o = ch*256 + t;
  float s = bl[o];
  #pragma unroll 8
  for (int c=0;c<192;++c) s = fmaf(v0[c], wl[c*1024 + o], s);
  o1g[b*1024 + o] = s;
}

__global__ __launch_bounds__(256) void headB_kernel(const float* __restrict__ o1g,
    const float* __restrict__ wm1, const float* __restrict__ bm1,
    float* __restrict__ h1g){
  __shared__ alignas(16) float vo[1024];
  int b = blockIdx.x >> 1, ch = blockIdx.x & 1, t = threadIdx.x;
  ((float4*)vo)[t] = ((const float4*)(o1g + b*1024))[t];
  __syncthreads();
  int o = ch*256 + t;
  float s = bm1[o];
  #pragma unroll 8
  for (int c=0;c<1024;++c) s = fmaf(vo[c], wm1[c*512 + o], s);
  h1g[b*512 + o] = lrelu(s);
}

__global__ __launch_bounds__(256) void headC_kernel(const float* __restrict__ h1g,
    const float* __restrict__ wm2, const float* __restrict__ bm2,
    const float* __restrict__ wm3, const float* __restrict__ bm3,
    float* __restrict__ out){
  __shared__ alignas(16) float vh[512];
  __shared__ float h2[256];
  int b = blockIdx.x, t = threadIdx.x;
  ((float2*)vh)[t] = ((const float2*)(h1g + b*512))[t];
  __syncthreads();
  float s = bm2[t];
  #pragma unroll 8
  for (int c=0;c<512;++c) s = fmaf(vh[c], wm2[c*256 + t], s);
  h2[t] = lrelu(s);
  __syncthreads();
  if (t < 3){
    float s2 = bm3[t];
    #pragma unroll 8
    for (int c=0;c<256;++c) s2 = fmaf(h2[c], wm3[c*3 + t], s2);
    out[b*3 + t] = s2;
  }
}

extern "C" void kernel_launch(void* const* d_in, const int* in_sizes, int n_in,
                              void* d_out, int out_size, void* d_ws, size_t ws_size,
                              hipStream_t stream) {
  const float* x   = (const float*)d_in[0];
  const float* pos = (const float*)d_in[1];
  const float* w1a = (const float*)d_in[3];
  const float* b1a = (const float*)d_in[4];
  const float* w1b = (const float*)d_in[5];
  const float* b1b = (const float*)d_in[6];
  const float* w1c = (const float*)d_in[7];
  const float* b1c = (const float*)d_in[8];
  const float* w2  = (const float*)d_in[9];
  const float* b2  = (const float*)d_in[10];
  const float* wl  = (const float*)d_in[11];
  const float* bl  = (const float*)d_in[12];
  const float* wm1 = (const float*)d_in[13];
  const float* bm1 = (const float*)d_in[14];
  const float* wm2 = (const float*)d_in[15];
  const float* bm2 = (const float*)d_in[16];
  const float* wm3 = (const float*)d_in[17];
  const float* bm3 = (const float*)d_in[18];
  float* out = (float*)d_out;

  float* ws_f  = (float*)d_ws;
  float* xx    = ws_f;                    // 262144 f
  float* x1    = xx + 262144;             // 4194304 f (16 MB)
  float* sq2   = x1 + 4194304;            // 65536 f
  int*   idx1  = (int*)(sq2 + 65536);     // 655360 i
  int*   idx2  = idx1 + 655360;           // 655360 i
  float* q2    = (float*)(idx2 + 655360); // 8388608 f (32 MB)
  float* r2    = q2 + 8388608;            // 8388608 f (32 MB)
  float* wcomb = r2 + 8388608;            // 16384 f
  float* fmean = wcomb + 16384;           // 12288 f
  float* o1g   = fmean + 12288;           // 65536 f
  float* h1g   = o1g + 65536;             // 32768 f
  float* seedd = h1g + 32768;             // 655360 f
  int*   seedi = (int*)(seedd + 655360);  // 655360 i
  float* Tbuf  = (float*)(seedi + 655360);// 65536 f
  int*   cnt4  = (int*)(Tbuf + 65536);    // 262144 i
  // Temporal overlays (consumed before qr2 writes q2/r2):
  float* bdh1  = r2;                      // knn1: 2621440 f
  int*   bih1  = (int*)(r2 + 2621440);    // knn1: 2621440 i
  float2* surv = (float2*)q2;             // knn2 survivors: 65536*4*30*8B

  prep_fused<<<368, 256, 0, stream>>>(x, pos, w2, xx, wcomb, fmean);
  knn1_kernel<<<1024, 256, 0, stream>>>(xx, bdh1, bih1);
  merge4_kernel<<<256, 256, 0, stream>>>(bdh1, bih1, idx1);
  edgeconv1_kernel<<<1024, 256, 0, stream>>>(xx, idx1, w1a, b1a, w1b, b1b, w1c, b1c, x1, sq2);
  knn2_thresh<<<256, 256, 0, stream>>>(x1, sq2, seedd, seedi, Tbuf);
  knn2_scan<<<1024, 256, 0, stream>>>(x1, sq2, Tbuf, surv, cnt4);
  knn2_select<<<256, 256, 0, stream>>>(seedd, seedi, surv, cnt4, idx2);
  qr2_kernel<<<256, 256, 0, stream>>>(x1, wcomb, b2, q2, r2);
  ec2_gather_kernel<<<8192, 256, 0, stream>>>(q2, r2, idx2, fmean);
  mean1_kernel<<<256, 256, 0, stream>>>(x1, fmean);
  headA_kernel<<<256, 256, 0, stream>>>(fmean, wl, bl, o1g);
  headB_kernel<<<128, 256, 0, stream>>>(o1g, wm1, bm1, h1g);
  headC_kernel<<<64, 256, 0, stream>>>(h1g, wm2, bm2, wm3, bm3, out);
}

// Round 15
// 955.580 us; speedup vs baseline: 8.6593x; 1.0018x over previous
//
#include <hip/hip_runtime.h>
#include <float.h>

#define NB 64
#define NP 1024
#define KNN 10
#define SCAP 30   // survivors per (point, j-chunk)

__device__ __forceinline__ float lrelu(float v){ return v >= 0.0f ? v : 0.01f*v; }

// sorted-ascending bubble insert; strict < keeps earlier-inserted (lower j) on ties.
// Only static data flow (no runtime-indexed register arrays — R6 spill lesson).
#define TOP10_INSERT(dk_, ik_, bd_, bi_)              \
  { float dk=dk_; int ik=ik_;                         \
    _Pragma("unroll")                                 \
    for (int s=0;s<KNN;++s){                          \
      bool sw = dk < bd_[s];                          \
      float td=bd_[s]; int ti=bi_[s];                 \
      bd_[s]=sw?dk:td; bi_[s]=sw?ik:ti;               \
      dk=sw?td:dk;     ik=sw?ti:ik; } }

// ---------------- fused prep: build xx, wcomb, zero fmean ----------------
__global__ void prep_fused(const float* __restrict__ x, const float* __restrict__ pos,
                           const float* __restrict__ w2,
                           float* __restrict__ xx, float* __restrict__ wcomb,
                           float* __restrict__ fmean){
  int tid = blockIdx.x*256 + threadIdx.x;   // grid 368 -> 94208 threads
  if (tid < 65536){
    float4 v;
    v.x = x[tid];
    v.y = pos[3*tid+0];
    v.z = pos[3*tid+1];
    v.w = pos[3*tid+2];
    ((float4*)xx)[tid] = v;
  } else if (tid < 65536+16384){
    int i = tid - 65536;
    int op = i >> 6, c = i & 63;
    if (op < 128){
      wcomb[i] = w2[(64+c)*128 + op];
    } else {
      int o = op - 128;
      wcomb[i] = w2[c*128 + o] - w2[(64+c)*128 + o];
    }
  } else {
    int i = tid - 65536 - 16384;
    if (i < NB*192) fmean[i] = 0.0f;
  }
}

// ---------------- knn1: 4-dim features, 4 i-quarters x 4 j-quarters ----------------
__global__ __launch_bounds__(256,2) void knn1_kernel(const float* __restrict__ xx,
                                                     float* __restrict__ bdh1,
                                                     int* __restrict__ bih1){
  __shared__ alignas(16) float sf[256*4];   // 4 KB j-quarter points
  __shared__ float ssq[256];
  int bid = blockIdx.x;        // 1024 = 64 b x 4 iq x 4 jq
  int b  = bid >> 4;
  int iq = (bid >> 2) & 3;
  int jq = bid & 3;
  int t = threadIdx.x;
  {
    float4 v = ((const float4*)xx)[(size_t)b*NP + jq*256 + t];
    ((float4*)sf)[t] = v;
    ssq[t] = ((v.x*v.x + v.y*v.y) + v.z*v.z) + v.w*v.w;
  }
  __syncthreads();
  int il = iq*256 + t;
  int n = b*NP + il;
  float4 fi = ((const float4*)xx)[n];
  float sqi = ((fi.x*fi.x + fi.y*fi.y) + fi.z*fi.z) + fi.w*fi.w;
  float bd[KNN]; int bi[KNN];
  #pragma unroll
  for (int s=0;s<KNN;++s){ bd[s]=FLT_MAX; bi[s]=0; }
  #pragma unroll 1
  for (int j=0;j<256;++j){
    float4 fj = ((float4*)sf)[j];
    float dot = fi.x*fj.x + fi.y*fj.y + fi.z*fj.z + fi.w*fj.w;
    float d2 = (sqi + ssq[j]) - 2.0f*dot;
    if (d2 < bd[KNN-1]){
      TOP10_INSERT(d2, jq*256+j, bd, bi);
    }
  }
  #pragma unroll
  for (int s=0;s<KNN;++s){
    bdh1[((size_t)n*4 + jq)*KNN + s] = bd[s];
    bih1[((size_t)n*4 + jq)*KNN + s] = bi[s];
  }
}

// ---------------- edgeconv1: 4 threads/point, 16 outputs, 2-edge batch, h in LDS ----------------
// Fused: (a) merge4 of knn1 quarter-lists in prolog (thread t<64, 1 pt each);
// (b) x1-mean block reduction in epilogue -> atomicAdd fmean[0:64].
// Weight ds_reads amortized over 2 edges; h rows in LDS (R11/R12 spill lessons);
// live set ~48 floats.
__global__ __launch_bounds__(256,2) void edgeconv1_kernel(
    const float* __restrict__ xx,
    const float* __restrict__ bdh1, const int* __restrict__ bih1,
    const float* __restrict__ w1a, const float* __restrict__ b1a,
    const float* __restrict__ w1b, const float* __restrict__ b1b,
    const float* __restrict__ w1c, const float* __restrict__ b1c,
    float* __restrict__ x1, float* __restrict__ sq2, float* __restrict__ fmean){
  __shared__ alignas(16) float swa[512];     //  2 KB w1a [c][o]
  __shared__ alignas(16) float swb[4096];    // 16 KB w1b [c][o]
  __shared__ alignas(16) float swc[4096];    // 16 KB w1c [c][o]
  __shared__ float sba[64], sbb[64], sbc[64];
  __shared__ float hx0[64*65];               // 16.6 KB edge-0 h rows
  __shared__ float hx1[64*65];               // 16.6 KB edge-1 h rows
  __shared__ int   sidx[64*KNN];             // 2.5 KB merged idx1 for block's points
  int t = threadIdx.x;
  int b  = blockIdx.x >> 4;  // batch
  int g  = blockIdx.x & 15;  // point group
  for (int i=t; i<128;  i+=256) ((float4*)swa)[i] = ((const float4*)w1a)[i];
  for (int i=t; i<1024; i+=256) ((float4*)swb)[i] = ((const float4*)w1b)[i];
  for (int i=t; i<1024; i+=256) ((float4*)swc)[i] = ((const float4*)w1c)[i];
  if (t < 64){ sba[t]=b1a[t]; sbb[t]=b1b[t]; sbc[t]=b1c[t]; }

  // ---- fused merge4: thread t<64 merges point (b, g*64+t)'s 4 sorted lists
  if (t < 64){
    int nm = b*NP + g*64 + t;
    float A[KNN]; int Ai[KNN];
    #pragma unroll
    for (int s=0;s<KNN;++s){
      A[s]  = bdh1[(size_t)nm*4*KNN + s];
      Ai[s] = bih1[(size_t)nm*4*KNN + s];
    }
    #pragma unroll
    for (int q2i=1;q2i<4;++q2i){
      float T[KNN]; int Ti[KNN];
      #pragma unroll
      for (int s=0;s<KNN;++s){
        T[s]  = bdh1[((size_t)nm*4+q2i)*KNN + s];
        Ti[s] = bih1[((size_t)nm*4+q2i)*KNN + s];
      }
      float O[KNN]; int Oi[KNN];
      #pragma unroll
      for (int s=0;s<KNN;++s){
        bool ta = A[0] <= T[0];
        O[s]  = ta ? A[0]  : T[0];
        Oi[s] = ta ? Ai[0] : Ti[0];
        #pragma unroll
        for (int u=0;u<KNN-1;++u){
          A[u]  = ta ? A[u+1]  : A[u];
          Ai[u] = ta ? Ai[u+1] : Ai[u];
          T[u]  = ta ? T[u]    : T[u+1];
          Ti[u] = ta ? Ti[u]   : Ti[u+1];
        }
      }
      #pragma unroll
      for (int s=0;s<KNN;++s){ A[s]=O[s]; Ai[s]=Oi[s]; }
    }
    #pragma unroll
    for (int s=0;s<KNN;++s) sidx[t*KNN+s] = Ai[s];
  }
  __syncthreads();

  int p  = t >> 2;           // local point 0..63
  int q  = t & 3;            // channel quarter
  int cb = q*16;
  int n  = b*NP + g*64 + p;
  float* h0row = &hx0[p*65];
  float* h1row = &hx1[p*65];

  float4 fi = ((const float4*)xx)[n];
  float acc[16];
  #pragma unroll
  for (int o=0;o<16;++o) acc[o]=0.0f;

  #pragma unroll 1
  for (int kp=0; kp<5; ++kp){
    int j0 = sidx[p*KNN + kp*2];
    int j1 = sidx[p*KNN + kp*2 + 1];
    float4 fj0 = ((const float4*)xx)[b*NP + j0];
    float4 fj1 = ((const float4*)xx)[b*NP + j1];
    float e0[8], e1[8];
    e0[0]=fi.x; e0[1]=fi.y; e0[2]=fi.z; e0[3]=fi.w;
    e0[4]=fj0.x-fi.x; e0[5]=fj0.y-fi.y; e0[6]=fj0.z-fi.z; e0[7]=fj0.w-fi.w;
    e1[0]=fi.x; e1[1]=fi.y; e1[2]=fi.z; e1[3]=fi.w;
    e1[4]=fj1.x-fi.x; e1[5]=fj1.y-fi.y; e1[6]=fj1.z-fi.z; e1[7]=fj1.w-fi.w;

    // ---- layer a: 8 -> my 16 channels, both edges share weight reads
    {
      float pr0[16], pr1[16];
      #pragma unroll
      for (int o=0;o<16;++o){ float bb=sba[cb+o]; pr0[o]=bb; pr1[o]=bb; }
      #pragma unroll
      for (int c=0;c<8;++c){
        #pragma unroll
        for (int o4=0;o4<4;++o4){
          float4 w = *(const float4*)&swa[c*64 + cb + o4*4];
          pr0[o4*4+0]=fmaf(e0[c],w.x,pr0[o4*4+0]);
          pr0[o4*4+1]=fmaf(e0[c],w.y,pr0[o4*4+1]);
          pr0[o4*4+2]=fmaf(e0[c],w.z,pr0[o4*4+2]);
          pr0[o4*4+3]=fmaf(e0[c],w.w,pr0[o4*4+3]);
          pr1[o4*4+0]=fmaf(e1[c],w.x,pr1[o4*4+0]);
          pr1[o4*4+1]=fmaf(e1[c],w.y,pr1[o4*4+1]);
          pr1[o4*4+2]=fmaf(e1[c],w.z,pr1[o4*4+2]);
          pr1[o4*4+3]=fmaf(e1[c],w.w,pr1[o4*4+3]);
        }
      }
      #pragma unroll
      for (int o=0;o<16;++o){ h0row[cb+o]=lrelu(pr0[o]); h1row[cb+o]=lrelu(pr1[o]); }
    }
    __syncthreads();

    // ---- layer b: full h rows from LDS, my 16 outputs, both edges
    float pr0[16], pr1[16];
    #pragma unroll
    for (int o=0;o<16;++o){ float bb=sbb[cb+o]; pr0[o]=bb; pr1[o]=bb; }
    #pragma unroll 4
    for (int c=0;c<64;++c){
      float hv0 = h0row[c];
      float hv1 = h1row[c];
      #pragma unroll
      for (int o4=0;o4<4;++o4){
        float4 w = *(const float4*)&swb[c*64 + cb + o4*4];
        pr0[o4*4+0]=fmaf(hv0,w.x,pr0[o4*4+0]);
        pr0[o4*4+1]=fmaf(hv0,w.y,pr0[o4*4+1]);
        pr0[o4*4+2]=fmaf(hv0,w.z,pr0[o4*4+2]);
        pr0[o4*4+3]=fmaf(hv0,w.w,pr0[o4*4+3]);
        pr1[o4*4+0]=fmaf(hv1,w.x,pr1[o4*4+0]);
        pr1[o4*4+1]=fmaf(hv1,w.y,pr1[o4*4+1]);
        pr1[o4*4+2]=fmaf(hv1,w.z,pr1[o4*4+2]);
        pr1[o4*4+3]=fmaf(hv1,w.w,pr1[o4*4+3]);
      }
    }
    __syncthreads();              // all h1 reads done before overwrite
    #pragma unroll
    for (int o=0;o<16;++o){ h0row[cb+o]=lrelu(pr0[o]); h1row[cb+o]=lrelu(pr1[o]); }
    __syncthreads();

    // ---- layer c: accumulate my 16 outputs, both edges
    #pragma unroll
    for (int o=0;o<16;++o){ float bb=sbc[cb+o]; pr0[o]=bb; pr1[o]=bb; }
    #pragma unroll 4
    for (int c=0;c<64;++c){
      float hv0 = h0row[c];
      float hv1 = h1row[c];
      #pragma unroll
      for (int o4=0;o4<4;++o4){
        float4 w = *(const float4*)&swc[c*64 + cb + o4*4];
        pr0[o4*4+0]=fmaf(hv0,w.x,pr0[o4*4+0]);
        pr0[o4*4+1]=fmaf(hv0,w.y,pr0[o4*4+1]);
        pr0[o4*4+2]=fmaf(hv0,w.z,pr0[o4*4+2]);
        pr0[o4*4+3]=fmaf(hv0,w.w,pr0[o4*4+3]);
        pr1[o4*4+0]=fmaf(hv1,w.x,pr1[o4*4+0]);
        pr1[o4*4+1]=fmaf(hv1,w.y,pr1[o4*4+1]);
        pr1[o4*4+2]=fmaf(hv1,w.z,pr1[o4*4+2]);
        pr1[o4*4+3]=fmaf(hv1,w.w,pr1[o4*4+3]);
      }
    }
    #pragma unroll
    for (int o=0;o<16;++o) acc[o] += lrelu(pr0[o]) + lrelu(pr1[o]);
    __syncthreads();              // rows free for next pair
  }

  // x1 write + sq2
  float s = 0.0f;
  #pragma unroll
  for (int o=0;o<16;o+=4){
    float4 v; v.x=acc[o]; v.y=acc[o+1]; v.z=acc[o+2]; v.w=acc[o+3];
    *(float4*)&x1[(size_t)n*64 + cb + o] = v;
    s = fmaf(acc[o],acc[o], fmaf(acc[o+1],acc[o+1], fmaf(acc[o+2],acc[o+2], fmaf(acc[o+3],acc[o+3], s))));
  }
  s += __shfl_xor(s, 1);
  s += __shfl_xor(s, 2);
  if (q == 0) sq2[n] = s;

  // ---- fused x1-mean partial: block covers 64 points of batch b
  #pragma unroll
  for (int o=0;o<16;++o) h0row[cb+o] = acc[o];
  __syncthreads();
  if (t < 64){
    float s2 = 0.0f;
    #pragma unroll 8
    for (int p2=0;p2<64;++p2) s2 += hx0[p2*65 + t];
    atomicAdd(&fmean[b*192 + t], s2);
  }
}

// ---------------- knn2 phase A: exact top-10 over j in [0,256) + threshold ----------------
__global__ __launch_bounds__(256,1) void knn2_thresh(const float* __restrict__ x1,
    const float* __restrict__ sq2,
    float* __restrict__ seed_d, int* __restrict__ seed_i, float* __restrict__ Tout){
  __shared__ alignas(16) float sj[64*64];    // 16 KB
  __shared__ float ssq[64];
  int b  = blockIdx.x >> 2;
  int ig = blockIdx.x & 3;
  int t = threadIdx.x;
  int n = b*NP + ig*256 + t;
  float xi[64];
  #pragma unroll
  for (int c=0;c<64;c+=4){
    float4 v = *(const float4*)&x1[(size_t)n*64+c];
    xi[c]=v.x; xi[c+1]=v.y; xi[c+2]=v.z; xi[c+3]=v.w;
  }
  float sqi = sq2[n];
  float bd[KNN]; int bi[KNN];
  #pragma unroll
  for (int s=0;s<KNN;++s){ bd[s]=FLT_MAX; bi[s]=0; }
  for (int tile=0; tile<4; ++tile){
    __syncthreads();
    const float4* src = (const float4*)(x1 + ((size_t)b*NP + tile*64)*64);
    for (int u=t; u<1024; u+=256) ((float4*)sj)[u] = src[u];
    if (t < 64) ssq[t] = sq2[b*NP + tile*64 + t];
    __syncthreads();
    #pragma unroll 1
    for (int j=0;j<64;++j){
      float dot = 0.0f;
      #pragma unroll
      for (int c=0;c<64;c+=4){
        float4 v = *(const float4*)&sj[j*64+c];
        dot = fmaf(xi[c+0],v.x,dot); dot = fmaf(xi[c+1],v.y,dot);
        dot = fmaf(xi[c+2],v.z,dot); dot = fmaf(xi[c+3],v.w,dot);
      }
      float d2 = (sqi + ssq[j]) - 2.0f*dot;
      if (d2 < bd[KNN-1]){
        TOP10_INSERT(d2, tile*64+j, bd, bi);
      }
    }
  }
  #pragma unroll
  for (int s=0;s<KNN;++s){
    seed_d[(size_t)n*KNN + s] = bd[s];
    seed_i[(size_t)n*KNN + s] = bi[s];
  }
  Tout[n] = bd[KNN-1];
}

// ---------------- knn2 phase B: filtered scan of j in [256,1024), 4 chunks ----------------
__global__ __launch_bounds__(256,2) void knn2_scan(const float* __restrict__ x1,
    const float* __restrict__ sq2, const float* __restrict__ Tin,
    float2* __restrict__ surv, int* __restrict__ cnt4){
  __shared__ alignas(16) float sj[96*64];    // 24 KB
  __shared__ float ssq[96];
  int bid = blockIdx.x;     // 1024 = 64 b x 4 ig x 4 jc
  int b  = bid >> 4;
  int ig = (bid >> 2) & 3;
  int jc = bid & 3;
  int t = threadIdx.x;
  int n = b*NP + ig*256 + t;
  float xi[64];
  #pragma unroll
  for (int c=0;c<64;c+=4){
    float4 v = *(const float4*)&x1[(size_t)n*64+c];
    xi[c]=v.x; xi[c+1]=v.y; xi[c+2]=v.z; xi[c+3]=v.w;
  }
  float sqi = sq2[n];
  float thr = Tin[n];
  int cnt = 0;
  float2* mybuf = surv + ((size_t)n*4 + jc)*SCAP;
  int jbase0 = 256 + jc*192;
  for (int tile=0; tile<2; ++tile){
    int jb = jbase0 + tile*96;
    __syncthreads();
    const float4* src = (const float4*)(x1 + ((size_t)b*NP + jb)*64);
    for (int u=t; u<1536; u+=256) ((float4*)sj)[u] = src[u];
    if (t < 96) ssq[t] = sq2[b*NP + jb + t];
    __syncthreads();
    #pragma unroll 1
    for (int j=0;j<96;++j){
      float dot = 0.0f;
      #pragma unroll
      for (int c=0;c<64;c+=4){
        float4 v = *(const float4*)&sj[j*64+c];
        dot = fmaf(xi[c+0],v.x,dot); dot = fmaf(xi[c+1],v.y,dot);
        dot = fmaf(xi[c+2],v.z,dot); dot = fmaf(xi[c+3],v.w,dot);
      }
      float d2 = (sqi + ssq[j]) - 2.0f*dot;
      if (d2 <= thr && cnt < SCAP){
        float2 e; e.x = d2; e.y = __int_as_float(jb + j);
        mybuf[cnt] = e;
        cnt++;
      }
    }
  }
  cnt4[(size_t)n*4 + jc] = cnt;
}

// ---------------- knn2 phase C: replay survivors into seed list ----------------
__global__ void knn2_select(const float* __restrict__ seed_d, const int* __restrict__ seed_i,
    const float2* __restrict__ surv, const int* __restrict__ cnt4,
    int* __restrict__ idx2){
  int n = blockIdx.x*256 + threadIdx.x;
  float bd[KNN]; int bi[KNN];
  #pragma unroll
  for (int s=0;s<KNN;++s){
    bd[s] = seed_d[(size_t)n*KNN + s];
    bi[s] = seed_i[(size_t)n*KNN + s];
  }
  #pragma unroll 1
  for (int c=0;c<4;++c){
    int nc = cnt4[(size_t)n*4 + c];
    const float2* buf = surv + ((size_t)n*4 + c)*SCAP;
    #pragma unroll 1
    for (int k=0;k<nc;++k){
      float2 e = buf[k];
      float d = e.x; int j = __float_as_int(e.y);
      if (d < bd[KNN-1]){
        TOP10_INSERT(d, j, bd, bi);
      }
    }
  }
  #pragma unroll
  for (int s=0;s<KNN;++s) idx2[(size_t)n*KNN+s] = bi[s];
}

// ---------------- q/r GEMM for edgeconv2: q=x1*Wbot, r=x1*(Wtop-Wbot)+b ----------------
__global__ __launch_bounds__(256,1) void qr2_kernel(const float* __restrict__ x1,
    const float* __restrict__ wcombg, const float* __restrict__ b2,
    float* __restrict__ q2, float* __restrict__ r2){
  __shared__ alignas(16) float sw[16384];    // 64 KB
  __shared__ float sb2[128];
  int t = threadIdx.x;
  for (int u=t; u<4096; u+=256) ((float4*)sw)[u] = ((const float4*)wcombg)[u];
  if (t < 128) sb2[t] = b2[t];
  __syncthreads();
  int n = blockIdx.x*256 + t;
  float xi[64];
  #pragma unroll
  for (int c=0;c<64;c+=4){
    float4 v = *(const float4*)&x1[(size_t)n*64+c];
    xi[c]=v.x; xi[c+1]=v.y; xi[c+2]=v.z; xi[c+3]=v.w;
  }
  #pragma unroll 1
  for (int op=0; op<128; op+=4){
    float q0=0,q1=0,q2a=0,q3=0, r0,r1,r2a,r3;
    r0=sb2[op]; r1=sb2[op+1]; r2a=sb2[op+2]; r3=sb2[op+3];
    #pragma unroll
    for (int c=0;c<64;c+=4){
      float4 a0 = *(const float4*)&sw[(op+0)*64+c];
      float4 a1 = *(const float4*)&sw[(op+1)*64+c];
      float4 a2 = *(const float4*)&sw[(op+2)*64+c];
      float4 a3 = *(const float4*)&sw[(op+3)*64+c];
      float4 c0 = *(const float4*)&sw[(128+op+0)*64+c];
      float4 c1 = *(const float4*)&sw[(128+op+1)*64+c];
      float4 c2 = *(const float4*)&sw[(128+op+2)*64+c];
      float4 c3 = *(const float4*)&sw[(128+op+3)*64+c];
      q0=fmaf(xi[c],a0.x,q0); q0=fmaf(xi[c+1],a0.y,q0); q0=fmaf(xi[c+2],a0.z,q0); q0=fmaf(xi[c+3],a0.w,q0);
      q1=fmaf(xi[c],a1.x,q1); q1=fmaf(xi[c+1],a1.y,q1); q1=fmaf(xi[c+2],a1.z,q1); q1=fmaf(xi[c+3],a1.w,q1);
      q2a=fmaf(xi[c],a2.x,q2a); q2a=fmaf(xi[c+1],a2.y,q2a); q2a=fmaf(xi[c+2],a2.z,q2a); q2a=fmaf(xi[c+3],a2.w,q2a);
      q3=fmaf(xi[c],a3.x,q3); q3=fmaf(xi[c+1],a3.y,q3); q3=fmaf(xi[c+2],a3.z,q3); q3=fmaf(xi[c+3],a3.w,q3);
      r0=fmaf(xi[c],c0.x,r0); r0=fmaf(xi[c+1],c0.y,r0); r0=fmaf(xi[c+2],c0.z,r0); r0=fmaf(xi[c+3],c0.w,r0);
      r1=fmaf(xi[c],c1.x,r1); r1=fmaf(xi[c+1],c1.y,r1); r1=fmaf(xi[c+2],c1.z,r1); r1=fmaf(xi[c+3],c1.w,r1);
      r2a=fmaf(xi[c],c2.x,r2a); r2a=fmaf(xi[c+1],c2.y,r2a); r2a=fmaf(xi[c+2],c2.z,r2a); r2a=fmaf(xi[c+3],c2.w,r2a);
      r3=fmaf(xi[c],c3.x,r3); r3=fmaf(xi[c+1],c3.y,r3); r3=fmaf(xi[c+2],c3.z,r3); r3=fmaf(xi[c+3],c3.w,r3);
    }
    float4 qv; qv.x=q0; qv.y=q1; qv.z=q2a; qv.w=q3;
    float4 rv; rv.x=r0; rv.y=r1; rv.z=r2a; rv.w=r3;
    *(float4*)&q2[(size_t)n*128+op] = qv;
    *(float4*)&r2[(size_t)n*128+op] = rv;
  }
}

// ---------------- edgeconv2 gather + fused mean (never materialize x2) ----------------
__global__ __launch_bounds__(256,4) void ec2_gather_kernel(
    const float* __restrict__ q2, const float* __restrict__ r2,
    const int* __restrict__ idx2, float* __restrict__ fmean){
  __shared__ alignas(16) float4 red[256];
  int t = threadIdx.x;
  int b = blockIdx.x >> 7, blk = blockIdx.x & 127;
  int p = t >> 5, c4 = t & 31;
  int n = b*NP + blk*8 + p;
  float4 r = *(const float4*)&r2[(size_t)n*128 + c4*4];
  float4 acc; acc.x=0; acc.y=0; acc.z=0; acc.w=0;
  #pragma unroll 1
  for (int k=0;k<KNN;++k){
    int j = idx2[n*KNN+k];
    float4 qv = *(const float4*)&q2[((size_t)b*NP + j)*128 + c4*4];
    acc.x += lrelu(r.x+qv.x);
    acc.y += lrelu(r.y+qv.y);
    acc.z += lrelu(r.z+qv.z);
    acc.w += lrelu(r.w+qv.w);
  }
  red[t] = acc;
  __syncthreads();
  if (t < 128){ float4 o = red[t+128]; red[t].x+=o.x; red[t].y+=o.y; red[t].z+=o.z; red[t].w+=o.w; }
  __syncthreads();
  if (t < 64){ float4 o = red[t+64]; red[t].x+=o.x; red[t].y+=o.y; red[t].z+=o.z; red[t].w+=o.w; }
  __syncthreads();
  if (t < 32){
    float4 s = red[t]; float4 o = red[t+32];
    s.x+=o.x; s.y+=o.y; s.z+=o.z; s.w+=o.w;
    float* dst = &fmean[b*192 + 64 + c4*4];
    atomicAdd(dst+0, s.x); atomicAdd(dst+1, s.y);
    atomicAdd(dst+2, s.z); atomicAdd(dst+3, s.w);
  }
}

// ---------------- head, split for parallelism ----------------
__global__ __launch_bounds__(256) void headA_kernel(const float* __restrict__ fmean,
    const float* __restrict__ wl, const float* __restrict__ bl,
    float* __restrict__ o1g){
  __shared__ float v0[192];
  int b = blockIdx.x >> 2, ch = blockIdx.x & 3, t = threadIdx.x;
  if (t < 192) v0[t] = fmean[b*192 + t] * (1.0f/1024.0f);
  __syncthreads();
  int o = ch*256 + t;
  float s = bl[o];
  #pragma unroll 8
  for (int c=0;c<192;++c) s = fmaf(v0[c], wl[c*1024 + o], s);
  o1g[b*1024 + o] = s;
}

__global__ __launch_bounds__(256) void headB_kernel(const float* __restrict__ o1g,
    const float* __restrict__ wm1, const float* __restrict__ bm1,
    float* __restrict__ h1g){
  __shared__ alignas(16) float vo[1024];
  int b = blockIdx.x >> 1, ch = blockIdx.x & 1, t = threadIdx.x;
  ((float4*)vo)[t] = ((const float4*)(o1g + b*1024))[t];
  __syncthreads();
  int o = ch*256 + t;
  float s = bm1[o];
  #pragma unroll 8
  for (int c=0;c<1024;++c) s = fmaf(vo[c], wm1[c*512 + o], s);
  h1g[b*512 + o] = lrelu(s);
}

__global__ __launch_bounds__(256) void headC_kernel(const float* __restrict__ h1g,
    const float* __restrict__ wm2, const float* __restrict__ bm2,
    const float* __restrict__ wm3, const float* __restrict__ bm3,
    float* __restrict__ out){
  __shared__ alignas(16) float vh[512];
  __shared__ float h2[256];
  int b = blockIdx.x, t = threadIdx.x;
  ((float2*)vh)[t] = ((const float2*)(h1g + b*512))[t];
  __syncthreads();
  float s = bm2[t];
  #pragma unroll 8
  for (int c=0;c<512;++c) s = fmaf(vh[c], wm2[c*256 + t], s);
  h2[t] = lrelu(s);
  __syncthreads();
  if (t < 3){
    float s2 = bm3[t];
    #pragma unroll 8
    for (int c=0;c<256;++c) s2 = fmaf(h2[c], wm3[c*3 + t], s2);
    out[b*3 + t] = s2;
  }
}

extern "C" void kernel_launch(void* const* d_in, const int* in_sizes, int n_in,
                              void* d_out, int out_size, void* d_ws, size_t ws_size,
                              hipStream_t stream) {
  const float* x   = (const float*)d_in[0];
  const float* pos = (const float*)d_in[1];
  const float* w1a = (const float*)d_in[3];
  const float* b1a = (const float*)d_in[4];
  const float* w1b = (const float*)d_in[5];
  const float* b1b = (const float*)d_in[6];
  const float* w1c = (const float*)d_in[7];
  const float* b1c = (const float*)d_in[8];
  const float* w2  = (const float*)d_in[9];
  const float* b2  = (const float*)d_in[10];
  const float* wl  = (const float*)d_in[11];
  const float* bl  = (const float*)d_in[12];
  const float* wm1 = (const float*)d_in[13];
  const float* bm1 = (const float*)d_in[14];
  const float* wm2 = (const float*)d_in[15];
  const float* bm2 = (const float*)d_in[16];
  const float* wm3 = (const float*)d_in[17];
  const float* bm3 = (const float*)d_in[18];
  float* out = (float*)d_out;

  float* ws_f  = (float*)d_ws;
  float* xx    = ws_f;                    // 262144 f
  float* x1    = xx + 262144;             // 4194304 f (16 MB)
  float* sq2   = x1 + 4194304;            // 65536 f
  int*   idx2  = (int*)(sq2 + 65536);     // 655360 i
  float* q2    = (float*)(idx2 + 655360); // 8388608 f (32 MB)
  float* r2    = q2 + 8388608;            // 8388608 f (32 MB)
  float* wcomb = r2 + 8388608;            // 16384 f
  float* fmean = wcomb + 16384;           // 12288 f
  float* o1g   = fmean + 12288;           // 65536 f
  float* h1g   = o1g + 65536;             // 32768 f
  float* seedd = h1g + 32768;             // 655360 f
  int*   seedi = (int*)(seedd + 655360);  // 655360 i
  float* Tbuf  = (float*)(seedi + 655360);// 65536 f
  int*   cnt4  = (int*)(Tbuf + 65536);    // 262144 i
  // Temporal overlays (consumed before qr2 writes q2/r2):
  float* bdh1  = r2;                      // knn1: 2621440 f (read by edgeconv1 merge)
  int*   bih1  = (int*)(r2 + 2621440);    // knn1: 2621440 i
  float2* surv = (float2*)q2;             // knn2 survivors: 65536*4*30*8B

  prep_fused<<<368, 256, 0, stream>>>(x, pos, w2, xx, wcomb, fmean);
  knn1_kernel<<<1024, 256, 0, stream>>>(xx, bdh1, bih1);
  edgeconv1_kernel<<<1024, 256, 0, stream>>>(xx, bdh1, bih1, w1a, b1a, w1b, b1b, w1c, b1c, x1, sq2, fmean);
  knn2_thresh<<<256, 256, 0, stream>>>(x1, sq2, seedd, seedi, Tbuf);
  knn2_scan<<<1024, 256, 0, stream>>>(x1, sq2, Tbuf, surv, cnt4);
  knn2_select<<<256, 256, 0, stream>>>(seedd, seedi, surv, cnt4, idx2);
  qr2_kernel<<<256, 256, 0, stream>>>(x1, wcomb, b2, q2, r2);
  ec2_gather_kernel<<<8192, 256, 0, stream>>>(q2, r2, idx2, fmean);
  headA_kernel<<<256, 256, 0, stream>>>(fmean, wl, bl, o1g);
  headB_kernel<<<128, 256, 0, stream>>>(o1g, wm1, bm1, h1g);
  headC_kernel<<<64, 256, 0, stream>>>(h1g, wm2, bm2, wm3, bm3, out);
}